// Round 8
// baseline (481.623 us; speedup 1.0000x reference)
//
#include <hip/hip_runtime.h>
#include <hip/hip_bf16.h>
#include <math.h>

// ---------------------------------------------------------------------------
// GATv2 2-layer + linear head, MI355X (gfx950)
// gemm_dual: round-6 proven version (BN=128 dual-z, 2-buffer ping-pong,
//   48KB LDS -> 3 blocks/CU, packed coalesced staging, full drain per K-step).
//   Round-7's counted-vmcnt 3-buffer variant REGRESSED (72KB LDS -> 2
//   blocks/CU lost more overlap than the counted waits gained) -- reverted.
// Dispatch-count reduction (this round): 13 -> 10 kernels.
//   - fused_scan: single-block 1024-thread hierarchical scan replaces
//     deg_block_reduce + scan_bsums + deg_scan_apply (3 dispatches -> 1).
//   - prep_inputs: cvt_f16_tiled and prep_weights merged into one dispatch
//     (disjoint blockIdx ranges).
// gat_node: round-6 version (depth-2 named slots, packed mode-0 write).
// ---------------------------------------------------------------------------

#define IN_DIM 256
#define HIDHC 256   // HEADS*HID
#define HID 64
#define OUT_DIM 40

using half8  = __attribute__((ext_vector_type(8))) _Float16;
using half4  = __attribute__((ext_vector_type(4))) _Float16;
using half2v = __attribute__((ext_vector_type(2))) _Float16;
using f32x4  = __attribute__((ext_vector_type(4))) float;

__device__ __forceinline__ void gload16(const void* g, void* l) {
    __builtin_amdgcn_global_load_lds(
        (const __attribute__((address_space(1))) void*)g,
        (__attribute__((address_space(3))) void*)l, 16, 0, 0);
}

// -------------------- CSR build --------------------

__global__ void edge_hist(const int* __restrict__ dst, int* __restrict__ deg, int E) {
    int i = blockIdx.x * blockDim.x + threadIdx.x;
    if (i < E) atomicAdd(&deg[dst[i]], 1);
}

// single-block hierarchical inclusive scan of deg[0..n) -> offsets[1..n],
// cursor[i] = exclusive prefix. Replaces the 3-kernel cascade.
__global__ __launch_bounds__(1024) void fused_scan(
    const int* __restrict__ deg, int* __restrict__ offsets,
    int* __restrict__ cursor, int n)
{
    __shared__ int carry;
    __shared__ int wsums[16];
    int tid = threadIdx.x;
    int lane = tid & 63, wv = tid >> 6;
    if (tid == 0) { carry = 0; offsets[0] = 0; }
    __syncthreads();
    for (int base = 0; base < n; base += 1024) {
        int i = base + tid;
        int v = (i < n) ? deg[i] : 0;
        int inc = v;
        #pragma unroll
        for (int off = 1; off < 64; off <<= 1) {
            int t = __shfl_up(inc, off, 64);
            if (lane >= off) inc += t;
        }
        if (lane == 63) wsums[wv] = inc;
        __syncthreads();                       // A: wsums visible
        int add = carry;
        for (int wj = 0; wj < wv; ++wj) add += wsums[wj];
        int incl = inc + add;
        if (i < n) { offsets[i + 1] = incl; cursor[i] = incl - v; }
        __syncthreads();                       // B: all reads of carry/wsums done
        if (tid == 1023) carry = incl;         // chunk total (carry-inclusive)
        __syncthreads();                       // C: carry visible for next chunk
    }
}

__global__ void edge_scatter(const int* __restrict__ src, const int* __restrict__ dst,
                             int* __restrict__ cursor, int* __restrict__ csr_src, int E) {
    int i = blockIdx.x * blockDim.x + threadIdx.x;
    if (i < E) {
        int p = atomicAdd(&cursor[dst[i]], 1);
        csr_src[p] = src[i];
    }
}

// -------------------- input prep (packed staging layouts, fused) ------------
// Packed A layout: (node,k) -> (node>>7)*32768 + (k>>3)*1024 + (node&127)*8 + (k&7)
// Packed W layout: (n,k) -> (n>>7)*32768 + (k>>5)*4096 + ((k>>3)&3)*1024
//                           + (n&127)*8 + (k&7)
// Blocks [0, nb_cvt): fp32->fp16 tiled conversion of x (4 elems/thread).
// Blocks [nb_cvt, nb_cvt+1024): weight transpose+pack (widx = blk - nb_cvt;
//   wsel = widx>>8 picks Wl1/Wr1/Wl2/Wr2, k = widx&255, nn = tid).

__global__ void prep_inputs(const float* __restrict__ x, _Float16* __restrict__ Af,
                            const float* __restrict__ W0, const float* __restrict__ W1,
                            const float* __restrict__ W2, const float* __restrict__ W3,
                            _Float16* __restrict__ T, int n4, int nb_cvt) {
    if ((int)blockIdx.x < nb_cvt) {
        int i = blockIdx.x * blockDim.x + threadIdx.x;
        if (i >= n4) return;
        float4 v = ((const float4*)x)[i];
        half4 h = { (_Float16)v.x, (_Float16)v.y, (_Float16)v.z, (_Float16)v.w };
        int node = i >> 6;
        int kb = (i & 63) * 4;
        size_t a = (size_t)(node >> 7) * 32768 + (size_t)(kb >> 3) * 1024
                 + (size_t)(node & 127) * 8 + (kb & 7);
        *(half4*)(Af + a) = h;
    } else {
        int widx = blockIdx.x - nb_cvt;
        int wsel = widx >> 8, k = widx & 255, nn = threadIdx.x;
        const float* Wsel = (wsel == 0) ? W0 : (wsel == 1) ? W1
                          : (wsel == 2) ? W2 : W3;
        float v = Wsel[k * 256 + nn];
        size_t a = (size_t)wsel * 65536
                 + (size_t)(nn >> 7) * 32768 + (size_t)(k >> 5) * 4096
                 + (size_t)((k >> 3) & 3) * 1024 + (size_t)(nn & 127) * 8 + (k & 7);
        T[a] = (_Float16)v;
    }
}

// -------------------- dual MFMA GEMM (BN=128, packed staging) ---------------
// C0[M,256] = A@W0 + b0, C1[M,256] = A@W1 + b1, fp16 in/out, fp32 accum.
// 128x128 tile, BK=32 (8 iters), 8 waves: z = w>>2 picks (W,bias,C).
// A staged once per K-step (shared by both z halves); staging loads are
// CONTIGUOUS: thread tid reads packed[tile_base + kt*4096 + tid*8].

__global__ __launch_bounds__(512) void gemm_dual(
    const _Float16* __restrict__ Apk,
    const _Float16* __restrict__ W0, const float* __restrict__ b0, _Float16* __restrict__ C0,
    const _Float16* __restrict__ W1, const float* __restrict__ b1, _Float16* __restrict__ C1,
    int M)
{
    __shared__ __align__(16) _Float16 sA[2][4096];        // 128x32 per buf
    __shared__ __align__(16) _Float16 sW[2][2][4096];     // [buf][z][128x32]

    int tid = threadIdx.x;
    int bm = blockIdx.x * 128;
    int bn = blockIdx.y * 128;

    int lane = tid & 63, w = tid >> 6;       // 8 waves
    int z  = w >> 2, wq = w & 3;
    int r = lane & 15, q = lane >> 4;
    int m0 = (wq >> 1) * 64, n0 = (wq & 1) * 64;

    const _Float16* Abase = Apk + (size_t)blockIdx.x * 32768;
    const _Float16* W0b   = W0  + (size_t)blockIdx.y * 32768;
    const _Float16* W1b   = W1  + (size_t)blockIdx.y * 32768;
    int go = tid * 8;                        // granule offset (elements)

    f32x4 acc[4][4];
    #pragma unroll
    for (int i = 0; i < 4; ++i)
        #pragma unroll
        for (int j = 0; j < 4; ++j) acc[i][j] = (f32x4)0.f;

    // preload tile 0 into buffer 0 (fully coalesced: lane-consecutive 16B)
    gload16(Abase + go, &sA[0][go]);
    gload16(W0b + go, &sW[0][0][go]);
    gload16(W1b + go, &sW[0][1][go]);
    __builtin_amdgcn_s_waitcnt(0);   // drain LDS-DMA
    __syncthreads();

    #pragma unroll 1
    for (int kt = 0; kt < 8; ++kt) {
        int buf = kt & 1;
        if (kt < 7) {
            int k0 = (kt + 1) * 4096;
            gload16(Abase + k0 + go, &sA[buf ^ 1][go]);
            gload16(W0b + k0 + go, &sW[buf ^ 1][0][go]);
            gload16(W1b + k0 + go, &sW[buf ^ 1][1][go]);
        }
        half8 a[4], b[4];
        #pragma unroll
        for (int i = 0; i < 4; ++i) {
            a[i] = *(const half8*)(&sA[buf][(q * 128 + m0 + i * 16 + r) * 8]);
            b[i] = *(const half8*)(&sW[buf][z][(q * 128 + n0 + i * 16 + r) * 8]);
        }
        #pragma unroll
        for (int i = 0; i < 4; ++i)
            #pragma unroll
            for (int j = 0; j < 4; ++j)
                acc[i][j] = __builtin_amdgcn_mfma_f32_16x16x32_f16(a[i], b[j], acc[i][j], 0, 0, 0);
        __builtin_amdgcn_s_waitcnt(0);   // drain prefetch DMA before buffer swap
        __syncthreads();
    }

    const float* bias = z ? b1 : b0;
    _Float16*    C    = z ? C1 : C0;

    // epilogue: C/D layout col=lane&15, row=q*4+reg (C row-major for gat)
    float bv[4];
    #pragma unroll
    for (int j = 0; j < 4; ++j) bv[j] = bias[bn + n0 + j * 16 + r];
    #pragma unroll
    for (int i = 0; i < 4; ++i) {
        #pragma unroll
        for (int reg = 0; reg < 4; ++reg) {
            int orow = bm + m0 + i * 16 + q * 4 + reg;
            if (orow < M) {
                #pragma unroll
                for (int j = 0; j < 4; ++j)
                    C[(size_t)orow * 256 + bn + n0 + j * 16 + r] =
                        (_Float16)(acc[i][j][reg] + bv[j]);
            }
        }
    }
}

// -------------------- GAT node kernel: half-wave-per-edge ---------------------
// 1 node/wave, 12500 blocks (dynamic balancing). Adjacency row preloaded into
// idxv (1 coalesced load, deg<=64); per-pair src via __shfl. Depth-2 gather
// pipeline, pair loop unrolled x2 with named slots (no rotation movs).
// deg>64 -> scalar fallback. mode 0 writes PACKED layout (next gemm's A).

__global__ __launch_bounds__(256) void gat_node(
    const _Float16* __restrict__ xl, const _Float16* __restrict__ xr,
    const float* __restrict__ att, const float* __restrict__ bias,
    const int* __restrict__ offsets, const int* __restrict__ csr_src,
    void* __restrict__ out0, int n, int mode)
{
    int wid = threadIdx.x >> 6;
    int node = (blockIdx.x << 2) + wid;
    if (node >= n) return;
    int lane = threadIdx.x & 63;
    int H = lane >> 5;
    int p = lane & 31;

    const half2v c02 = { (_Float16)0.2f, (_Float16)0.2f };

    half8 xrh = *(const half8*)(xr + (size_t)node * HIDHC + p * 8);
    half2v xr01 = __builtin_shufflevector(xrh, xrh, 0, 1);
    half2v xr23 = __builtin_shufflevector(xrh, xrh, 2, 3);
    half2v xr45 = __builtin_shufflevector(xrh, xrh, 4, 5);
    half2v xr67 = __builtin_shufflevector(xrh, xrh, 6, 7);

    float4 af0 = *(const float4*)(att + p * 8);
    float4 af1 = *(const float4*)(att + p * 8 + 4);
    half2v at01 = { (_Float16)af0.x, (_Float16)af0.y };
    half2v at23 = { (_Float16)af0.z, (_Float16)af0.w };
    half2v at45 = { (_Float16)af1.x, (_Float16)af1.y };
    half2v at67 = { (_Float16)af1.z, (_Float16)af1.w };

    float acc[8];
    #pragma unroll
    for (int k = 0; k < 8; ++k) acc[k] = 0.f;
    float d = 0.f;

    auto edge_compute = [&](half8 h) {
        half2v h01 = __builtin_shufflevector(h, h, 0, 1);
        half2v h23 = __builtin_shufflevector(h, h, 2, 3);
        half2v h45 = __builtin_shufflevector(h, h, 4, 5);
        half2v h67 = __builtin_shufflevector(h, h, 6, 7);
        half2v s01 = h01 + xr01, s23 = h23 + xr23, s45 = h45 + xr45, s67 = h67 + xr67;
        half2v l01 = __builtin_elementwise_max(s01, s01 * c02);
        half2v l23 = __builtin_elementwise_max(s23, s23 * c02);
        half2v l45 = __builtin_elementwise_max(s45, s45 * c02);
        half2v l67 = __builtin_elementwise_max(s67, s67 * c02);
        float e = __builtin_amdgcn_fdot2(l01, at01, 0.f, false);
        e = __builtin_amdgcn_fdot2(l23, at23, e, false);
        e = __builtin_amdgcn_fdot2(l45, at45, e, false);
        e = __builtin_amdgcn_fdot2(l67, at67, e, false);
        e += __shfl_xor(e, 1);
        e += __shfl_xor(e, 2);
        e += __shfl_xor(e, 4);
        float pw = __expf(e);
        d += pw;
        #pragma unroll
        for (int k = 0; k < 8; ++k) acc[k] = fmaf(pw, (float)h[k], acc[k]);
    };

    int j0 = __builtin_amdgcn_readfirstlane(offsets[node]);
    int j1 = __builtin_amdgcn_readfirstlane(offsets[node + 1]);
    int deg = j1 - j0;

    // --- fast path: adjacency row in one register (deg<=64) ---
    int fast = min(deg, 64);
    int npf = fast >> 1;                 // pairs handled by the pipeline
    int idxv = 0;
    if (lane < fast) idxv = csr_src[j0 + lane];

    half8 hA, hB;                        // depth-2, named slots (no rotation)
    if (npf > 0) { int s = __shfl(idxv, 0 + H, 64); hA = *(const half8*)(xl + (size_t)s * HIDHC + p * 8); }
    if (npf > 1) { int s = __shfl(idxv, 2 + H, 64); hB = *(const half8*)(xl + (size_t)s * HIDHC + p * 8); }
    int t = 0;
    for (; t + 4 <= npf; t += 2) {       // steady state: compute 2, prefetch 2
        half8 ha = hA, hb = hB;
        { int s = __shfl(idxv, (t + 2) * 2 + H, 64); hA = *(const half8*)(xl + (size_t)s * HIDHC + p * 8); }
        { int s = __shfl(idxv, (t + 3) * 2 + H, 64); hB = *(const half8*)(xl + (size_t)s * HIDHC + p * 8); }
        edge_compute(ha);
        edge_compute(hb);
    }
    if (t + 2 <= npf) {                  // 2 or 3 pairs left
        half8 ha = hA, hb = hB;
        if (t + 2 < npf) { int s = __shfl(idxv, (t + 2) * 2 + H, 64); hA = *(const half8*)(xl + (size_t)s * HIDHC + p * 8); }
        edge_compute(ha);
        edge_compute(hb);
        t += 2;
    }
    if (t < npf) {                       // final pair
        edge_compute(hA);
    }

    // --- remainder: deg>64 pairs (rare) ---
    int j = j0 + (npf << 1);
    for (; j + 2 <= j1; j += 2) {
        int s0 = __builtin_amdgcn_readfirstlane(csr_src[j]);
        int s1 = __builtin_amdgcn_readfirstlane(csr_src[j + 1]);
        int s = H ? s1 : s0;
        half8 h = *(const half8*)(xl + (size_t)s * HIDHC + p * 8);
        edge_compute(h);
    }
    if (j < j1) {                        // odd leftover edge (H==0 half only)
        int s0 = __builtin_amdgcn_readfirstlane(csr_src[j]);
        half8 h = *(const half8*)(xl + (size_t)s0 * HIDHC + p * 8);
        half2v h01 = __builtin_shufflevector(h, h, 0, 1);
        half2v h23 = __builtin_shufflevector(h, h, 2, 3);
        half2v h45 = __builtin_shufflevector(h, h, 4, 5);
        half2v h67 = __builtin_shufflevector(h, h, 6, 7);
        half2v s01 = h01 + xr01, s23 = h23 + xr23, s45 = h45 + xr45, s67 = h67 + xr67;
        half2v l01 = __builtin_elementwise_max(s01, s01 * c02);
        half2v l23 = __builtin_elementwise_max(s23, s23 * c02);
        half2v l45 = __builtin_elementwise_max(s45, s45 * c02);
        half2v l67 = __builtin_elementwise_max(s67, s67 * c02);
        float e = __builtin_amdgcn_fdot2(l01, at01, 0.f, false);
        e = __builtin_amdgcn_fdot2(l23, at23, e, false);
        e = __builtin_amdgcn_fdot2(l45, at45, e, false);
        e = __builtin_amdgcn_fdot2(l67, at67, e, false);
        e += __shfl_xor(e, 1);
        e += __shfl_xor(e, 2);
        e += __shfl_xor(e, 4);
        float pw = (H == 0) ? __expf(e) : 0.f;
        d += pw;
        #pragma unroll
        for (int k = 0; k < 8; ++k) acc[k] = fmaf(pw, (float)h[k], acc[k]);
    }

    d += __shfl_xor(d, 32);
    #pragma unroll
    for (int k = 0; k < 8; ++k) acc[k] += __shfl_xor(acc[k], 32);

    float inv = 1.f / (d + 1e-16f);
    float o[8];
    #pragma unroll
    for (int k = 0; k < 8; ++k) o[k] = acc[k] * inv;

    if (mode == 0) {
        if (H == 0) {
            float4 b0 = *(const float4*)(bias + p * 8);
            float4 b1 = *(const float4*)(bias + p * 8 + 4);
            float bb[8] = { b0.x, b0.y, b0.z, b0.w, b1.x, b1.y, b1.z, b1.w };
            half8 hh;
            #pragma unroll
            for (int k = 0; k < 8; ++k) hh[k] = (_Float16)fmaxf(o[k] + bb[k], 0.f);
            // packed layout write: next gemm's A ([tile][kgroup=p][row][8])
            _Float16* dst = (_Float16*)out0 + (size_t)(node >> 7) * 32768
                          + (size_t)p * 1024 + (size_t)(node & 127) * 8;
            *(half8*)dst = hh;
        }
    } else {
        #pragma unroll
        for (int k = 0; k < 8; ++k) {
            o[k] += __shfl_xor(o[k], 8);
            o[k] += __shfl_xor(o[k], 16);
        }
        if (lane < 8) {
            float4 b0 = *(const float4*)(bias + p * 8);
            float4 b1 = *(const float4*)(bias + p * 8 + 4);
            float bb[8] = { b0.x, b0.y, b0.z, b0.w, b1.x, b1.y, b1.z, b1.w };
            float4 o0, o1;
            o0.x = fmaxf(o[0] * 0.25f + bb[0], 0.f);
            o0.y = fmaxf(o[1] * 0.25f + bb[1], 0.f);
            o0.z = fmaxf(o[2] * 0.25f + bb[2], 0.f);
            o0.w = fmaxf(o[3] * 0.25f + bb[3], 0.f);
            o1.x = fmaxf(o[4] * 0.25f + bb[4], 0.f);
            o1.y = fmaxf(o[5] * 0.25f + bb[5], 0.f);
            o1.z = fmaxf(o[6] * 0.25f + bb[6], 0.f);
            o1.w = fmaxf(o[7] * 0.25f + bb[7], 0.f);
            float* dst = (float*)out0 + (size_t)node * HID + p * 8;
            *(float4*)dst = o0;
            *(float4*)(dst + 4) = o1;
        }
    }
}

// -------------------- final linear: out[N,40] = h2[N,64] @ Wc[64,40] + bc --------------------

__global__ __launch_bounds__(256) void final_linear(
    const float* __restrict__ h2, const float* __restrict__ Wc,
    const float* __restrict__ bc, float* __restrict__ out, int n)
{
    __shared__ float Ws[HID * OUT_DIM];
    __shared__ float bs[OUT_DIM];
    __shared__ float hs[64][HID + 1];

    for (int i = threadIdx.x; i < HID * OUT_DIM; i += 256) Ws[i] = Wc[i];
    if (threadIdx.x < OUT_DIM) bs[threadIdx.x] = bc[threadIdx.x];

    int n0 = blockIdx.x * 64;
    for (int i = threadIdx.x; i < 64 * HID; i += 256) {
        int r = i >> 6, c = i & 63;
        int node = n0 + r;
        hs[r][c] = (node < n) ? h2[(size_t)node * HID + c] : 0.f;
    }
    __syncthreads();

    for (int idx = threadIdx.x; idx < 64 * OUT_DIM; idx += 256) {
        int r = idx / OUT_DIM, o = idx % OUT_DIM;
        int node = n0 + r;
        if (node < n) {
            float s = bs[o];
            #pragma unroll
            for (int c = 0; c < HID; ++c) s = fmaf(hs[r][c], Ws[c * OUT_DIM + o], s);
            out[(size_t)node * OUT_DIM + o] = s;
        }
    }
}

// -------------------- launch --------------------

extern "C" void kernel_launch(void* const* d_in, const int* in_sizes, int n_in,
                              void* d_out, int out_size, void* d_ws, size_t ws_size,
                              hipStream_t stream) {
    const int N = in_sizes[0] / IN_DIM;   // 50000
    const int E = in_sizes[1];            // 800000

    const float* x    = (const float*)d_in[0];
    const int*   src  = (const int*)d_in[1];
    const int*   dst  = (const int*)d_in[2];
    const float* Wl1  = (const float*)d_in[3];
    const float* bl1  = (const float*)d_in[4];
    const float* Wr1  = (const float*)d_in[5];
    const float* br1  = (const float*)d_in[6];
    const float* att1 = (const float*)d_in[7];
    const float* bias1= (const float*)d_in[8];
    const float* Wl2  = (const float*)d_in[9];
    const float* bl2  = (const float*)d_in[10];
    const float* Wr2  = (const float*)d_in[11];
    const float* br2  = (const float*)d_in[12];
    const float* att2 = (const float*)d_in[13];
    const float* bias2= (const float*)d_in[14];
    const float* Wc   = (const float*)d_in[15];
    const float* bc   = (const float*)d_in[16];

    char* ws = (char*)d_ws;
    size_t off = 0;
    const int NT = (N + 127) / 128;                                   // A tiles
    _Float16* xlh = (_Float16*)(ws + off); off += (size_t)N * HIDHC * 2;  // xl fp16 (row-major)
    _Float16* xrh = (_Float16*)(ws + off); off += (size_t)N * HIDHC * 2;  // xr fp16 (row-major)
    _Float16* Af  = (_Float16*)(ws + off); off += (size_t)NT * 32768 * 2; // x / h1 fp16 (PACKED)
    float*    h2  = (float*)(ws + off);    off += (size_t)N * HID * 4;
    _Float16* Wt  = (_Float16*)(ws + off); off += (size_t)4 * 65536 * 2;  // packed weights
    int* deg     = (int*)(ws + off); off += (size_t)N * 4;
    int* offsets = (int*)(ws + off); off += (size_t)(N + 1) * 4;
    int* cursor  = (int*)(ws + off); off += (size_t)N * 4;
    int* csr     = (int*)(ws + off); off += (size_t)E * 4;

    // CSR build + input prep (10 dispatches total incl. memsets)
    hipMemsetAsync(deg, 0, (size_t)N * 4, stream);
    if (N & 127)   // zero the tail tile of packed A (rows >= N)
        hipMemsetAsync(Af + (size_t)(NT - 1) * 32768, 0, 32768 * 2, stream);
    edge_hist<<<(E + 255) / 256, 256, 0, stream>>>(dst, deg, E);
    fused_scan<<<1, 1024, 0, stream>>>(deg, offsets, cursor, N);
    edge_scatter<<<(E + 255) / 256, 256, 0, stream>>>(src, dst, cursor, csr, E);
    const int n4 = N * HIDHC / 4;
    const int nb_cvt = (n4 + 255) / 256;
    prep_inputs<<<nb_cvt + 1024, 256, 0, stream>>>(x, Af, Wl1, Wr1, Wl2, Wr2,
                                                   Wt, n4, nb_cvt);

    const int KW = 65536;
    dim3 gg(NT, 2);
    // layer 1
    gemm_dual<<<gg, 512, 0, stream>>>(Af,
        Wt + 0 * KW, bl1, xlh,
        Wt + 1 * KW, br1, xrh, N);
    gat_node<<<(N + 3) / 4, 256, 0, stream>>>(xlh, xrh, att1, bias1, offsets, csr,
                                              (void*)Af, N, 0);
    // layer 2
    gemm_dual<<<gg, 512, 0, stream>>>(Af,
        Wt + 2 * KW, bl2, xlh,
        Wt + 3 * KW, br2, xrh, N);
    gat_node<<<(N + 3) / 4, 256, 0, stream>>>(xlh, xrh, att2, bias2, offsets, csr,
                                              (void*)h2, N, 1);
    // head
    final_linear<<<(N + 63) / 64, 256, 0, stream>>>(h2, Wc, bc, (float*)d_out, N);
}

// Round 9
// 435.537 us; speedup vs baseline: 1.1058x; 1.1058x over previous
//
#include <hip/hip_runtime.h>
#include <hip/hip_bf16.h>
#include <math.h>

// ---------------------------------------------------------------------------
// GATv2 2-layer + linear head, MI355X (gfx950)
// Round 9 = round-6 proven configuration (428us) restored:
//   - gemm_dual: BN=128 dual-z, 2-buffer ping-pong, 48KB LDS (3 blocks/CU),
//     packed coalesced staging (1KB/wave bursts). BN=256 (r5) and counted-
//     vmcnt 3-buffer (r7) variants both REGRESSED -- this is the local opt.
//   - CSR scan: 3-kernel PARALLEL cascade restored. Round-8's single-block
//     fused scan cost ~50us (49 serial latency-bound chunks on one CU);
//     dispatch-gap savings are ~us-scale -- never serialize real work.
//   - prep_inputs fusion KEPT (cvt + weight-pack, disjoint block ranges,
//     both halves parallel; one fewer dispatch, per-thread work unchanged).
// gat_node: round-6 version (depth-2 named slots, packed mode-0 write).
//   At its L2-refetch floor: FETCH pinned ~192MB, 3 scheduling attacks flat.
// ---------------------------------------------------------------------------

#define IN_DIM 256
#define HIDHC 256   // HEADS*HID
#define HID 64
#define OUT_DIM 40

using half8  = __attribute__((ext_vector_type(8))) _Float16;
using half4  = __attribute__((ext_vector_type(4))) _Float16;
using half2v = __attribute__((ext_vector_type(2))) _Float16;
using f32x4  = __attribute__((ext_vector_type(4))) float;

__device__ __forceinline__ void gload16(const void* g, void* l) {
    __builtin_amdgcn_global_load_lds(
        (const __attribute__((address_space(1))) void*)g,
        (__attribute__((address_space(3))) void*)l, 16, 0, 0);
}

// -------------------- CSR build (parallel 3-phase scan) --------------------

__global__ void edge_hist(const int* __restrict__ dst, int* __restrict__ deg, int E) {
    int i = blockIdx.x * blockDim.x + threadIdx.x;
    if (i < E) atomicAdd(&deg[dst[i]], 1);
}

__global__ void deg_block_reduce(const int* __restrict__ deg, int* __restrict__ bsum, int n) {
    int i = blockIdx.x * 256 + threadIdx.x;
    int v = (i < n) ? deg[i] : 0;
    #pragma unroll
    for (int off = 32; off; off >>= 1) v += __shfl_xor(v, off, 64);
    __shared__ int ws[4];
    int lane = threadIdx.x & 63, wid = threadIdx.x >> 6;
    if (lane == 0) ws[wid] = v;
    __syncthreads();
    if (threadIdx.x == 0) bsum[blockIdx.x] = ws[0] + ws[1] + ws[2] + ws[3];
}

__global__ void scan_bsums(const int* __restrict__ bsum, int* __restrict__ bpre, int nb) {
    __shared__ int s[256];
    int tid = threadIdx.x;
    int orig = (tid < nb) ? bsum[tid] : 0;
    s[tid] = orig;
    __syncthreads();
    #pragma unroll
    for (int off = 1; off < 256; off <<= 1) {
        int t = (tid >= off) ? s[tid - off] : 0;
        __syncthreads();
        s[tid] += t;
        __syncthreads();
    }
    if (tid < nb) bpre[tid] = s[tid] - orig;
}

__global__ void deg_scan_apply(const int* __restrict__ deg, const int* __restrict__ bpre,
                               int* __restrict__ offsets, int* __restrict__ cursor, int n) {
    int i = blockIdx.x * 256 + threadIdx.x;
    int lane = threadIdx.x & 63, wid = threadIdx.x >> 6;
    int v = (i < n) ? deg[i] : 0;
    int inc = v;
    #pragma unroll
    for (int off = 1; off < 64; off <<= 1) {
        int t = __shfl_up(inc, off, 64);
        if (lane >= off) inc += t;
    }
    __shared__ int ws[4];
    if (lane == 63) ws[wid] = inc;
    __syncthreads();
    int add = bpre[blockIdx.x];
    for (int w = 0; w < wid; ++w) add += ws[w];
    int incl = inc + add;
    if (i < n) { offsets[i + 1] = incl; cursor[i] = incl - v; }
    if (i == 0) offsets[0] = 0;
}

__global__ void edge_scatter(const int* __restrict__ src, const int* __restrict__ dst,
                             int* __restrict__ cursor, int* __restrict__ csr_src, int E) {
    int i = blockIdx.x * blockDim.x + threadIdx.x;
    if (i < E) {
        int p = atomicAdd(&cursor[dst[i]], 1);
        csr_src[p] = src[i];
    }
}

// -------------------- input prep (packed staging layouts, fused) ------------
// Packed A layout: (node,k) -> (node>>7)*32768 + (k>>3)*1024 + (node&127)*8 + (k&7)
// Packed W layout: (n,k) -> (n>>7)*32768 + (k>>5)*4096 + ((k>>3)&3)*1024
//                           + (n&127)*8 + (k&7)
// Blocks [0, nb_cvt): fp32->fp16 tiled conversion of x (4 elems/thread).
// Blocks [nb_cvt, nb_cvt+1024): weight transpose+pack.

__global__ void prep_inputs(const float* __restrict__ x, _Float16* __restrict__ Af,
                            const float* __restrict__ W0, const float* __restrict__ W1,
                            const float* __restrict__ W2, const float* __restrict__ W3,
                            _Float16* __restrict__ T, int n4, int nb_cvt) {
    if ((int)blockIdx.x < nb_cvt) {
        int i = blockIdx.x * blockDim.x + threadIdx.x;
        if (i >= n4) return;
        float4 v = ((const float4*)x)[i];
        half4 h = { (_Float16)v.x, (_Float16)v.y, (_Float16)v.z, (_Float16)v.w };
        int node = i >> 6;
        int kb = (i & 63) * 4;
        size_t a = (size_t)(node >> 7) * 32768 + (size_t)(kb >> 3) * 1024
                 + (size_t)(node & 127) * 8 + (kb & 7);
        *(half4*)(Af + a) = h;
    } else {
        int widx = blockIdx.x - nb_cvt;
        int wsel = widx >> 8, k = widx & 255, nn = threadIdx.x;
        const float* Wsel = (wsel == 0) ? W0 : (wsel == 1) ? W1
                          : (wsel == 2) ? W2 : W3;
        float v = Wsel[k * 256 + nn];
        size_t a = (size_t)wsel * 65536
                 + (size_t)(nn >> 7) * 32768 + (size_t)(k >> 5) * 4096
                 + (size_t)((k >> 3) & 3) * 1024 + (size_t)(nn & 127) * 8 + (k & 7);
        T[a] = (_Float16)v;
    }
}

// -------------------- dual MFMA GEMM (BN=128, packed staging) ---------------
// C0[M,256] = A@W0 + b0, C1[M,256] = A@W1 + b1, fp16 in/out, fp32 accum.
// 128x128 tile, BK=32 (8 iters), 8 waves: z = w>>2 picks (W,bias,C).
// A staged once per K-step (shared by both z halves); staging loads are
// CONTIGUOUS: thread tid reads packed[tile_base + kt*4096 + tid*8].

__global__ __launch_bounds__(512) void gemm_dual(
    const _Float16* __restrict__ Apk,
    const _Float16* __restrict__ W0, const float* __restrict__ b0, _Float16* __restrict__ C0,
    const _Float16* __restrict__ W1, const float* __restrict__ b1, _Float16* __restrict__ C1,
    int M)
{
    __shared__ __align__(16) _Float16 sA[2][4096];        // 128x32 per buf
    __shared__ __align__(16) _Float16 sW[2][2][4096];     // [buf][z][128x32]

    int tid = threadIdx.x;
    int bm = blockIdx.x * 128;
    int bn = blockIdx.y * 128;

    int lane = tid & 63, w = tid >> 6;       // 8 waves
    int z  = w >> 2, wq = w & 3;
    int r = lane & 15, q = lane >> 4;
    int m0 = (wq >> 1) * 64, n0 = (wq & 1) * 64;

    const _Float16* Abase = Apk + (size_t)blockIdx.x * 32768;
    const _Float16* W0b   = W0  + (size_t)blockIdx.y * 32768;
    const _Float16* W1b   = W1  + (size_t)blockIdx.y * 32768;
    int go = tid * 8;                        // granule offset (elements)

    f32x4 acc[4][4];
    #pragma unroll
    for (int i = 0; i < 4; ++i)
        #pragma unroll
        for (int j = 0; j < 4; ++j) acc[i][j] = (f32x4)0.f;

    // preload tile 0 into buffer 0 (fully coalesced: lane-consecutive 16B)
    gload16(Abase + go, &sA[0][go]);
    gload16(W0b + go, &sW[0][0][go]);
    gload16(W1b + go, &sW[0][1][go]);
    __builtin_amdgcn_s_waitcnt(0);   // drain LDS-DMA
    __syncthreads();

    #pragma unroll 1
    for (int kt = 0; kt < 8; ++kt) {
        int buf = kt & 1;
        if (kt < 7) {
            int k0 = (kt + 1) * 4096;
            gload16(Abase + k0 + go, &sA[buf ^ 1][go]);
            gload16(W0b + k0 + go, &sW[buf ^ 1][0][go]);
            gload16(W1b + k0 + go, &sW[buf ^ 1][1][go]);
        }
        half8 a[4], b[4];
        #pragma unroll
        for (int i = 0; i < 4; ++i) {
            a[i] = *(const half8*)(&sA[buf][(q * 128 + m0 + i * 16 + r) * 8]);
            b[i] = *(const half8*)(&sW[buf][z][(q * 128 + n0 + i * 16 + r) * 8]);
        }
        #pragma unroll
        for (int i = 0; i < 4; ++i)
            #pragma unroll
            for (int j = 0; j < 4; ++j)
                acc[i][j] = __builtin_amdgcn_mfma_f32_16x16x32_f16(a[i], b[j], acc[i][j], 0, 0, 0);
        __builtin_amdgcn_s_waitcnt(0);   // drain prefetch DMA before buffer swap
        __syncthreads();
    }

    const float* bias = z ? b1 : b0;
    _Float16*    C    = z ? C1 : C0;

    // epilogue: C/D layout col=lane&15, row=q*4+reg (C row-major for gat)
    float bv[4];
    #pragma unroll
    for (int j = 0; j < 4; ++j) bv[j] = bias[bn + n0 + j * 16 + r];
    #pragma unroll
    for (int i = 0; i < 4; ++i) {
        #pragma unroll
        for (int reg = 0; reg < 4; ++reg) {
            int orow = bm + m0 + i * 16 + q * 4 + reg;
            if (orow < M) {
                #pragma unroll
                for (int j = 0; j < 4; ++j)
                    C[(size_t)orow * 256 + bn + n0 + j * 16 + r] =
                        (_Float16)(acc[i][j][reg] + bv[j]);
            }
        }
    }
}

// -------------------- GAT node kernel: half-wave-per-edge ---------------------
// 1 node/wave, 12500 blocks (dynamic balancing). Adjacency row preloaded into
// idxv (1 coalesced load, deg<=64); per-pair src via __shfl. Depth-2 gather
// pipeline, pair loop unrolled x2 with named slots (no rotation movs).
// deg>64 -> scalar fallback. mode 0 writes PACKED layout (next gemm's A).

__global__ __launch_bounds__(256) void gat_node(
    const _Float16* __restrict__ xl, const _Float16* __restrict__ xr,
    const float* __restrict__ att, const float* __restrict__ bias,
    const int* __restrict__ offsets, const int* __restrict__ csr_src,
    void* __restrict__ out0, int n, int mode)
{
    int wid = threadIdx.x >> 6;
    int node = (blockIdx.x << 2) + wid;
    if (node >= n) return;
    int lane = threadIdx.x & 63;
    int H = lane >> 5;
    int p = lane & 31;

    const half2v c02 = { (_Float16)0.2f, (_Float16)0.2f };

    half8 xrh = *(const half8*)(xr + (size_t)node * HIDHC + p * 8);
    half2v xr01 = __builtin_shufflevector(xrh, xrh, 0, 1);
    half2v xr23 = __builtin_shufflevector(xrh, xrh, 2, 3);
    half2v xr45 = __builtin_shufflevector(xrh, xrh, 4, 5);
    half2v xr67 = __builtin_shufflevector(xrh, xrh, 6, 7);

    float4 af0 = *(const float4*)(att + p * 8);
    float4 af1 = *(const float4*)(att + p * 8 + 4);
    half2v at01 = { (_Float16)af0.x, (_Float16)af0.y };
    half2v at23 = { (_Float16)af0.z, (_Float16)af0.w };
    half2v at45 = { (_Float16)af1.x, (_Float16)af1.y };
    half2v at67 = { (_Float16)af1.z, (_Float16)af1.w };

    float acc[8];
    #pragma unroll
    for (int k = 0; k < 8; ++k) acc[k] = 0.f;
    float d = 0.f;

    auto edge_compute = [&](half8 h) {
        half2v h01 = __builtin_shufflevector(h, h, 0, 1);
        half2v h23 = __builtin_shufflevector(h, h, 2, 3);
        half2v h45 = __builtin_shufflevector(h, h, 4, 5);
        half2v h67 = __builtin_shufflevector(h, h, 6, 7);
        half2v s01 = h01 + xr01, s23 = h23 + xr23, s45 = h45 + xr45, s67 = h67 + xr67;
        half2v l01 = __builtin_elementwise_max(s01, s01 * c02);
        half2v l23 = __builtin_elementwise_max(s23, s23 * c02);
        half2v l45 = __builtin_elementwise_max(s45, s45 * c02);
        half2v l67 = __builtin_elementwise_max(s67, s67 * c02);
        float e = __builtin_amdgcn_fdot2(l01, at01, 0.f, false);
        e = __builtin_amdgcn_fdot2(l23, at23, e, false);
        e = __builtin_amdgcn_fdot2(l45, at45, e, false);
        e = __builtin_amdgcn_fdot2(l67, at67, e, false);
        e += __shfl_xor(e, 1);
        e += __shfl_xor(e, 2);
        e += __shfl_xor(e, 4);
        float pw = __expf(e);
        d += pw;
        #pragma unroll
        for (int k = 0; k < 8; ++k) acc[k] = fmaf(pw, (float)h[k], acc[k]);
    };

    int j0 = __builtin_amdgcn_readfirstlane(offsets[node]);
    int j1 = __builtin_amdgcn_readfirstlane(offsets[node + 1]);
    int deg = j1 - j0;

    // --- fast path: adjacency row in one register (deg<=64) ---
    int fast = min(deg, 64);
    int npf = fast >> 1;                 // pairs handled by the pipeline
    int idxv = 0;
    if (lane < fast) idxv = csr_src[j0 + lane];

    half8 hA, hB;                        // depth-2, named slots (no rotation)
    if (npf > 0) { int s = __shfl(idxv, 0 + H, 64); hA = *(const half8*)(xl + (size_t)s * HIDHC + p * 8); }
    if (npf > 1) { int s = __shfl(idxv, 2 + H, 64); hB = *(const half8*)(xl + (size_t)s * HIDHC + p * 8); }
    int t = 0;
    for (; t + 4 <= npf; t += 2) {       // steady state: compute 2, prefetch 2
        half8 ha = hA, hb = hB;
        { int s = __shfl(idxv, (t + 2) * 2 + H, 64); hA = *(const half8*)(xl + (size_t)s * HIDHC + p * 8); }
        { int s = __shfl(idxv, (t + 3) * 2 + H, 64); hB = *(const half8*)(xl + (size_t)s * HIDHC + p * 8); }
        edge_compute(ha);
        edge_compute(hb);
    }
    if (t + 2 <= npf) {                  // 2 or 3 pairs left
        half8 ha = hA, hb = hB;
        if (t + 2 < npf) { int s = __shfl(idxv, (t + 2) * 2 + H, 64); hA = *(const half8*)(xl + (size_t)s * HIDHC + p * 8); }
        edge_compute(ha);
        edge_compute(hb);
        t += 2;
    }
    if (t < npf) {                       // final pair
        edge_compute(hA);
    }

    // --- remainder: deg>64 pairs (rare) ---
    int j = j0 + (npf << 1);
    for (; j + 2 <= j1; j += 2) {
        int s0 = __builtin_amdgcn_readfirstlane(csr_src[j]);
        int s1 = __builtin_amdgcn_readfirstlane(csr_src[j + 1]);
        int s = H ? s1 : s0;
        half8 h = *(const half8*)(xl + (size_t)s * HIDHC + p * 8);
        edge_compute(h);
    }
    if (j < j1) {                        // odd leftover edge (H==0 half only)
        int s0 = __builtin_amdgcn_readfirstlane(csr_src[j]);
        half8 h = *(const half8*)(xl + (size_t)s0 * HIDHC + p * 8);
        half2v h01 = __builtin_shufflevector(h, h, 0, 1);
        half2v h23 = __builtin_shufflevector(h, h, 2, 3);
        half2v h45 = __builtin_shufflevector(h, h, 4, 5);
        half2v h67 = __builtin_shufflevector(h, h, 6, 7);
        half2v s01 = h01 + xr01, s23 = h23 + xr23, s45 = h45 + xr45, s67 = h67 + xr67;
        half2v l01 = __builtin_elementwise_max(s01, s01 * c02);
        half2v l23 = __builtin_elementwise_max(s23, s23 * c02);
        half2v l45 = __builtin_elementwise_max(s45, s45 * c02);
        half2v l67 = __builtin_elementwise_max(s67, s67 * c02);
        float e = __builtin_amdgcn_fdot2(l01, at01, 0.f, false);
        e = __builtin_amdgcn_fdot2(l23, at23, e, false);
        e = __builtin_amdgcn_fdot2(l45, at45, e, false);
        e = __builtin_amdgcn_fdot2(l67, at67, e, false);
        e += __shfl_xor(e, 1);
        e += __shfl_xor(e, 2);
        e += __shfl_xor(e, 4);
        float pw = (H == 0) ? __expf(e) : 0.f;
        d += pw;
        #pragma unroll
        for (int k = 0; k < 8; ++k) acc[k] = fmaf(pw, (float)h[k], acc[k]);
    }

    d += __shfl_xor(d, 32);
    #pragma unroll
    for (int k = 0; k < 8; ++k) acc[k] += __shfl_xor(acc[k], 32);

    float inv = 1.f / (d + 1e-16f);
    float o[8];
    #pragma unroll
    for (int k = 0; k < 8; ++k) o[k] = acc[k] * inv;

    if (mode == 0) {
        if (H == 0) {
            float4 b0 = *(const float4*)(bias + p * 8);
            float4 b1 = *(const float4*)(bias + p * 8 + 4);
            float bb[8] = { b0.x, b0.y, b0.z, b0.w, b1.x, b1.y, b1.z, b1.w };
            half8 hh;
            #pragma unroll
            for (int k = 0; k < 8; ++k) hh[k] = (_Float16)fmaxf(o[k] + bb[k], 0.f);
            // packed layout write: next gemm's A ([tile][kgroup=p][row][8])
            _Float16* dst = (_Float16*)out0 + (size_t)(node >> 7) * 32768
                          + (size_t)p * 1024 + (size_t)(node & 127) * 8;
            *(half8*)dst = hh;
        }
    } else {
        #pragma unroll
        for (int k = 0; k < 8; ++k) {
            o[k] += __shfl_xor(o[k], 8);
            o[k] += __shfl_xor(o[k], 16);
        }
        if (lane < 8) {
            float4 b0 = *(const float4*)(bias + p * 8);
            float4 b1 = *(const float4*)(bias + p * 8 + 4);
            float bb[8] = { b0.x, b0.y, b0.z, b0.w, b1.x, b1.y, b1.z, b1.w };
            float4 o0, o1;
            o0.x = fmaxf(o[0] * 0.25f + bb[0], 0.f);
            o0.y = fmaxf(o[1] * 0.25f + bb[1], 0.f);
            o0.z = fmaxf(o[2] * 0.25f + bb[2], 0.f);
            o0.w = fmaxf(o[3] * 0.25f + bb[3], 0.f);
            o1.x = fmaxf(o[4] * 0.25f + bb[4], 0.f);
            o1.y = fmaxf(o[5] * 0.25f + bb[5], 0.f);
            o1.z = fmaxf(o[6] * 0.25f + bb[6], 0.f);
            o1.w = fmaxf(o[7] * 0.25f + bb[7], 0.f);
            float* dst = (float*)out0 + (size_t)node * HID + p * 8;
            *(float4*)dst = o0;
            *(float4*)(dst + 4) = o1;
        }
    }
}

// -------------------- final linear: out[N,40] = h2[N,64] @ Wc[64,40] + bc --------------------

__global__ __launch_bounds__(256) void final_linear(
    const float* __restrict__ h2, const float* __restrict__ Wc,
    const float* __restrict__ bc, float* __restrict__ out, int n)
{
    __shared__ float Ws[HID * OUT_DIM];
    __shared__ float bs[OUT_DIM];
    __shared__ float hs[64][HID + 1];

    for (int i = threadIdx.x; i < HID * OUT_DIM; i += 256) Ws[i] = Wc[i];
    if (threadIdx.x < OUT_DIM) bs[threadIdx.x] = bc[threadIdx.x];

    int n0 = blockIdx.x * 64;
    for (int i = threadIdx.x; i < 64 * HID; i += 256) {
        int r = i >> 6, c = i & 63;
        int node = n0 + r;
        hs[r][c] = (node < n) ? h2[(size_t)node * HID + c] : 0.f;
    }
    __syncthreads();

    for (int idx = threadIdx.x; idx < 64 * OUT_DIM; idx += 256) {
        int r = idx / OUT_DIM, o = idx % OUT_DIM;
        int node = n0 + r;
        if (node < n) {
            float s = bs[o];
            #pragma unroll
            for (int c = 0; c < HID; ++c) s = fmaf(hs[r][c], Ws[c * OUT_DIM + o], s);
            out[(size_t)node * OUT_DIM + o] = s;
        }
    }
}

// -------------------- launch --------------------

extern "C" void kernel_launch(void* const* d_in, const int* in_sizes, int n_in,
                              void* d_out, int out_size, void* d_ws, size_t ws_size,
                              hipStream_t stream) {
    const int N = in_sizes[0] / IN_DIM;   // 50000
    const int E = in_sizes[1];            // 800000

    const float* x    = (const float*)d_in[0];
    const int*   src  = (const int*)d_in[1];
    const int*   dst  = (const int*)d_in[2];
    const float* Wl1  = (const float*)d_in[3];
    const float* bl1  = (const float*)d_in[4];
    const float* Wr1  = (const float*)d_in[5];
    const float* br1  = (const float*)d_in[6];
    const float* att1 = (const float*)d_in[7];
    const float* bias1= (const float*)d_in[8];
    const float* Wl2  = (const float*)d_in[9];
    const float* bl2  = (const float*)d_in[10];
    const float* Wr2  = (const float*)d_in[11];
    const float* br2  = (const float*)d_in[12];
    const float* att2 = (const float*)d_in[13];
    const float* bias2= (const float*)d_in[14];
    const float* Wc   = (const float*)d_in[15];
    const float* bc   = (const float*)d_in[16];

    char* ws = (char*)d_ws;
    size_t off = 0;
    const int NT = (N + 127) / 128;                                   // A tiles
    _Float16* xlh = (_Float16*)(ws + off); off += (size_t)N * HIDHC * 2;  // xl fp16 (row-major)
    _Float16* xrh = (_Float16*)(ws + off); off += (size_t)N * HIDHC * 2;  // xr fp16 (row-major)
    _Float16* Af  = (_Float16*)(ws + off); off += (size_t)NT * 32768 * 2; // x / h1 fp16 (PACKED)
    float*    h2  = (float*)(ws + off);    off += (size_t)N * HID * 4;
    _Float16* Wt  = (_Float16*)(ws + off); off += (size_t)4 * 65536 * 2;  // packed weights
    int* deg     = (int*)(ws + off); off += (size_t)N * 4;
    int* offsets = (int*)(ws + off); off += (size_t)(N + 1) * 4;
    int* cursor  = (int*)(ws + off); off += (size_t)N * 4;
    int* csr     = (int*)(ws + off); off += (size_t)E * 4;
    int* bsum    = (int*)(ws + off); off += 256 * 4;
    int* bpre    = (int*)(ws + off); off += 256 * 4;

    const int NB = (N + 255) / 256;

    // CSR build (parallel scan) + input prep
    hipMemsetAsync(deg, 0, (size_t)N * 4, stream);
    if (N & 127)   // zero the tail tile of packed A (rows >= N)
        hipMemsetAsync(Af + (size_t)(NT - 1) * 32768, 0, 32768 * 2, stream);
    edge_hist<<<(E + 255) / 256, 256, 0, stream>>>(dst, deg, E);
    deg_block_reduce<<<NB, 256, 0, stream>>>(deg, bsum, N);
    scan_bsums<<<1, 256, 0, stream>>>(bsum, bpre, NB);
    deg_scan_apply<<<NB, 256, 0, stream>>>(deg, bpre, offsets, cursor, N);
    edge_scatter<<<(E + 255) / 256, 256, 0, stream>>>(src, dst, cursor, csr, E);
    const int n4 = N * HIDHC / 4;
    const int nb_cvt = (n4 + 255) / 256;
    prep_inputs<<<nb_cvt + 1024, 256, 0, stream>>>(x, Af, Wl1, Wr1, Wl2, Wr2,
                                                   Wt, n4, nb_cvt);

    const int KW = 65536;
    dim3 gg(NT, 2);
    // layer 1
    gemm_dual<<<gg, 512, 0, stream>>>(Af,
        Wt + 0 * KW, bl1, xlh,
        Wt + 1 * KW, br1, xrh, N);
    gat_node<<<(N + 3) / 4, 256, 0, stream>>>(xlh, xrh, att1, bias1, offsets, csr,
                                              (void*)Af, N, 0);
    // layer 2
    gemm_dual<<<gg, 512, 0, stream>>>(Af,
        Wt + 2 * KW, bl2, xlh,
        Wt + 3 * KW, br2, xrh, N);
    gat_node<<<(N + 3) / 4, 256, 0, stream>>>(xlh, xrh, att2, bias2, offsets, csr,
                                              (void*)h2, N, 1);
    // head
    final_linear<<<(N + 63) / 64, 256, 0, stream>>>(h2, Wc, bc, (float*)d_out, N);
}

// Round 10
// 415.489 us; speedup vs baseline: 1.1592x; 1.0483x over previous
//
#include <hip/hip_runtime.h>
#include <hip/hip_bf16.h>
#include <math.h>

// ---------------------------------------------------------------------------
// GATv2 2-layer + linear head, MI355X (gfx950)
// Round 10: co-scheduling of INDEPENDENT work (kernel bodies unchanged):
//   - hist_prep: edge_hist (atomics, latency-bound) runs in the same dispatch
//     as input prep (streaming, BW-bound), disjoint blockIdx ranges; hist
//     blocks first so they fill CUs while prep ramps.
//   - gemm_scatter: layer-1 gemm_dual and edge_scatter co-scheduled (scatter
//     independent of gemm; both must precede gat1). Scatter blocks first.
//   - deg_scan_apply: per-block inline prefix over bsum (196 ints) replaces
//     the single-block scan_bsums dispatch (~1us redundant adds per block).
//   Round-8 lesson: never serialize parallel work to save a launch; this
//   round's dual: co-schedule independent work in ONE launch.
// gemm body / gat_node / final_linear: byte-identical to round-6 proven best.
// ---------------------------------------------------------------------------

#define IN_DIM 256
#define HIDHC 256   // HEADS*HID
#define HID 64
#define OUT_DIM 40

using half8  = __attribute__((ext_vector_type(8))) _Float16;
using half4  = __attribute__((ext_vector_type(4))) _Float16;
using half2v = __attribute__((ext_vector_type(2))) _Float16;
using f32x4  = __attribute__((ext_vector_type(4))) float;

__device__ __forceinline__ void gload16(const void* g, void* l) {
    __builtin_amdgcn_global_load_lds(
        (const __attribute__((address_space(1))) void*)g,
        (__attribute__((address_space(3))) void*)l, 16, 0, 0);
}

// -------------------- CSR build --------------------

// merged: edge histogram || fp32->fp16 tiled cvt || weight transpose+pack
// Packed A layout: (node,k) -> (node>>7)*32768 + (k>>3)*1024 + (node&127)*8 + (k&7)
// Packed W layout: (n,k) -> (n>>7)*32768 + (k>>5)*4096 + ((k>>3)&3)*1024
//                           + (n&127)*8 + (k&7)
__global__ void hist_prep(const int* __restrict__ dst, int* __restrict__ deg,
                          int E, int nbh,
                          const float* __restrict__ x, _Float16* __restrict__ Af,
                          const float* __restrict__ W0, const float* __restrict__ W1,
                          const float* __restrict__ W2, const float* __restrict__ W3,
                          _Float16* __restrict__ T, int n4, int nb_cvt) {
    int bid = blockIdx.x;
    if (bid < nbh) {                       // edge histogram (atomics)
        int i = bid * 256 + threadIdx.x;
        if (i < E) atomicAdd(&deg[dst[i]], 1);
    } else if (bid < nbh + nb_cvt) {       // x fp32 -> fp16 packed
        int i = (bid - nbh) * 256 + threadIdx.x;
        if (i >= n4) return;
        float4 v = ((const float4*)x)[i];
        half4 h = { (_Float16)v.x, (_Float16)v.y, (_Float16)v.z, (_Float16)v.w };
        int node = i >> 6;
        int kb = (i & 63) * 4;
        size_t a = (size_t)(node >> 7) * 32768 + (size_t)(kb >> 3) * 1024
                 + (size_t)(node & 127) * 8 + (kb & 7);
        *(half4*)(Af + a) = h;
    } else {                               // weight transpose+pack
        int widx = bid - nbh - nb_cvt;
        int wsel = widx >> 8, k = widx & 255, nn = threadIdx.x;
        const float* Wsel = (wsel == 0) ? W0 : (wsel == 1) ? W1
                          : (wsel == 2) ? W2 : W3;
        float v = Wsel[k * 256 + nn];
        size_t a = (size_t)wsel * 65536
                 + (size_t)(nn >> 7) * 32768 + (size_t)(k >> 5) * 4096
                 + (size_t)((k >> 3) & 3) * 1024 + (size_t)(nn & 127) * 8 + (k & 7);
        T[a] = (_Float16)v;
    }
}

__global__ void deg_block_reduce(const int* __restrict__ deg, int* __restrict__ bsum, int n) {
    int i = blockIdx.x * 256 + threadIdx.x;
    int v = (i < n) ? deg[i] : 0;
    #pragma unroll
    for (int off = 32; off; off >>= 1) v += __shfl_xor(v, off, 64);
    __shared__ int ws[4];
    int lane = threadIdx.x & 63, wid = threadIdx.x >> 6;
    if (lane == 0) ws[wid] = v;
    __syncthreads();
    if (threadIdx.x == 0) bsum[blockIdx.x] = ws[0] + ws[1] + ws[2] + ws[3];
}

// apply with INLINE block-prefix over bsum (replaces scan_bsums dispatch):
// each block sums bsum[0..blockIdx.x) via a 256-thread reduction (nb<=256).
__global__ void deg_scan_apply(const int* __restrict__ deg, const int* __restrict__ bsum,
                               int* __restrict__ offsets, int* __restrict__ cursor,
                               int n, int nb) {
    int tid = threadIdx.x;
    int lane = tid & 63, wid = tid >> 6;

    // exclusive prefix of bsum for this block
    __shared__ int pws[4];
    __shared__ int sadd;
    int pv = (tid < nb && tid < (int)blockIdx.x) ? bsum[tid] : 0;
    #pragma unroll
    for (int off = 32; off; off >>= 1) pv += __shfl_xor(pv, off, 64);
    if (lane == 0) pws[wid] = pv;
    __syncthreads();
    if (tid == 0) sadd = pws[0] + pws[1] + pws[2] + pws[3];
    __syncthreads();

    int i = blockIdx.x * 256 + tid;
    int v = (i < n) ? deg[i] : 0;
    int inc = v;
    #pragma unroll
    for (int off = 1; off < 64; off <<= 1) {
        int t = __shfl_up(inc, off, 64);
        if (lane >= off) inc += t;
    }
    __shared__ int ws[4];
    if (lane == 63) ws[wid] = inc;
    __syncthreads();
    int add = sadd;
    for (int w = 0; w < wid; ++w) add += ws[w];
    int incl = inc + add;
    if (i < n) { offsets[i + 1] = incl; cursor[i] = incl - v; }
    if (i == 0) offsets[0] = 0;
}

// -------------------- dual MFMA GEMM tile (device body, round-6 proven) -----
// C0[M,256] = A@W0 + b0, C1[M,256] = A@W1 + b1, fp16 in/out, fp32 accum.
// 128x128 tile, BK=32 (8 iters), 8 waves: z = w>>2 picks (W,bias,C).
// sA: 2*4096 halves, sW: 2*2*4096 halves (48KB total).

__device__ __forceinline__ void gemm_tile(
    const _Float16* __restrict__ Apk,
    const _Float16* __restrict__ W0, const float* __restrict__ b0, _Float16* __restrict__ C0,
    const _Float16* __restrict__ W1, const float* __restrict__ b1, _Float16* __restrict__ C1,
    int M, int bx, int by, _Float16* sA, _Float16* sW)
{
    int tid = threadIdx.x;
    int bm = bx * 128;
    int bn = by * 128;

    int lane = tid & 63, w = tid >> 6;       // 8 waves
    int z  = w >> 2, wq = w & 3;
    int r = lane & 15, q = lane >> 4;
    int m0 = (wq >> 1) * 64, n0 = (wq & 1) * 64;

    const _Float16* Abase = Apk + (size_t)bx * 32768;
    const _Float16* W0b   = W0  + (size_t)by * 32768;
    const _Float16* W1b   = W1  + (size_t)by * 32768;
    int go = tid * 8;                        // granule offset (elements)

    f32x4 acc[4][4];
    #pragma unroll
    for (int i = 0; i < 4; ++i)
        #pragma unroll
        for (int j = 0; j < 4; ++j) acc[i][j] = (f32x4)0.f;

    // preload tile 0 into buffer 0 (fully coalesced: lane-consecutive 16B)
    gload16(Abase + go, sA + go);
    gload16(W0b + go, sW + go);
    gload16(W1b + go, sW + 4096 + go);
    __builtin_amdgcn_s_waitcnt(0);   // drain LDS-DMA
    __syncthreads();

    #pragma unroll 1
    for (int kt = 0; kt < 8; ++kt) {
        int buf = kt & 1;
        if (kt < 7) {
            int k0 = (kt + 1) * 4096;
            gload16(Abase + k0 + go, sA + (buf ^ 1) * 4096 + go);
            gload16(W0b + k0 + go, sW + ((buf ^ 1) * 2 + 0) * 4096 + go);
            gload16(W1b + k0 + go, sW + ((buf ^ 1) * 2 + 1) * 4096 + go);
        }
        half8 a[4], b[4];
        #pragma unroll
        for (int i = 0; i < 4; ++i) {
            a[i] = *(const half8*)(sA + buf * 4096 + (q * 128 + m0 + i * 16 + r) * 8);
            b[i] = *(const half8*)(sW + (buf * 2 + z) * 4096 + (q * 128 + n0 + i * 16 + r) * 8);
        }
        #pragma unroll
        for (int i = 0; i < 4; ++i)
            #pragma unroll
            for (int j = 0; j < 4; ++j)
                acc[i][j] = __builtin_amdgcn_mfma_f32_16x16x32_f16(a[i], b[j], acc[i][j], 0, 0, 0);
        __builtin_amdgcn_s_waitcnt(0);   // drain prefetch DMA before buffer swap
        __syncthreads();
    }

    const float* bias = z ? b1 : b0;
    _Float16*    C    = z ? C1 : C0;

    // epilogue: C/D layout col=lane&15, row=q*4+reg (C row-major for gat)
    float bv[4];
    #pragma unroll
    for (int j = 0; j < 4; ++j) bv[j] = bias[bn + n0 + j * 16 + r];
    #pragma unroll
    for (int i = 0; i < 4; ++i) {
        #pragma unroll
        for (int reg = 0; reg < 4; ++reg) {
            int orow = bm + m0 + i * 16 + q * 4 + reg;
            if (orow < M) {
                #pragma unroll
                for (int j = 0; j < 4; ++j)
                    C[(size_t)orow * 256 + bn + n0 + j * 16 + r] =
                        (_Float16)(acc[i][j][reg] + bv[j]);
            }
        }
    }
}

// layer-2 (and generic) standalone gemm
__global__ __launch_bounds__(512) void gemm_dual(
    const _Float16* __restrict__ Apk,
    const _Float16* __restrict__ W0, const float* __restrict__ b0, _Float16* __restrict__ C0,
    const _Float16* __restrict__ W1, const float* __restrict__ b1, _Float16* __restrict__ C1,
    int M)
{
    __shared__ __align__(16) _Float16 sA[2 * 4096];
    __shared__ __align__(16) _Float16 sW[2 * 2 * 4096];
    gemm_tile(Apk, W0, b0, C0, W1, b1, C1, M, blockIdx.x, blockIdx.y, sA, sW);
}

// layer-1 gemm co-scheduled with edge_scatter (independent; both precede gat1).
// Scatter blocks FIRST (latency-bound atomics fill CUs while gemm ramps).
__global__ __launch_bounds__(512) void gemm_scatter(
    const _Float16* __restrict__ Apk,
    const _Float16* __restrict__ W0, const float* __restrict__ b0, _Float16* __restrict__ C0,
    const _Float16* __restrict__ W1, const float* __restrict__ b1, _Float16* __restrict__ C1,
    int M, int nbs,
    const int* __restrict__ src, const int* __restrict__ dst,
    int* __restrict__ cursor, int* __restrict__ csr_src, int E)
{
    __shared__ __align__(16) _Float16 sA[2 * 4096];
    __shared__ __align__(16) _Float16 sW[2 * 2 * 4096];
    if ((int)blockIdx.x < nbs) {           // edge scatter
        int e = blockIdx.x * 512 + threadIdx.x;
        if (e < E) {
            int p = atomicAdd(&cursor[dst[e]], 1);
            csr_src[p] = src[e];
        }
        return;
    }
    int g = blockIdx.x - nbs;
    gemm_tile(Apk, W0, b0, C0, W1, b1, C1, M, g >> 1, g & 1, sA, sW);
}

// -------------------- GAT node kernel: half-wave-per-edge ---------------------
// 1 node/wave, 12500 blocks (dynamic balancing). Adjacency row preloaded into
// idxv (1 coalesced load, deg<=64); per-pair src via __shfl. Depth-2 gather
// pipeline, pair loop unrolled x2 with named slots (no rotation movs).
// deg>64 -> scalar fallback. mode 0 writes PACKED layout (next gemm's A).

__global__ __launch_bounds__(256) void gat_node(
    const _Float16* __restrict__ xl, const _Float16* __restrict__ xr,
    const float* __restrict__ att, const float* __restrict__ bias,
    const int* __restrict__ offsets, const int* __restrict__ csr_src,
    void* __restrict__ out0, int n, int mode)
{
    int wid = threadIdx.x >> 6;
    int node = (blockIdx.x << 2) + wid;
    if (node >= n) return;
    int lane = threadIdx.x & 63;
    int H = lane >> 5;
    int p = lane & 31;

    const half2v c02 = { (_Float16)0.2f, (_Float16)0.2f };

    half8 xrh = *(const half8*)(xr + (size_t)node * HIDHC + p * 8);
    half2v xr01 = __builtin_shufflevector(xrh, xrh, 0, 1);
    half2v xr23 = __builtin_shufflevector(xrh, xrh, 2, 3);
    half2v xr45 = __builtin_shufflevector(xrh, xrh, 4, 5);
    half2v xr67 = __builtin_shufflevector(xrh, xrh, 6, 7);

    float4 af0 = *(const float4*)(att + p * 8);
    float4 af1 = *(const float4*)(att + p * 8 + 4);
    half2v at01 = { (_Float16)af0.x, (_Float16)af0.y };
    half2v at23 = { (_Float16)af0.z, (_Float16)af0.w };
    half2v at45 = { (_Float16)af1.x, (_Float16)af1.y };
    half2v at67 = { (_Float16)af1.z, (_Float16)af1.w };

    float acc[8];
    #pragma unroll
    for (int k = 0; k < 8; ++k) acc[k] = 0.f;
    float d = 0.f;

    auto edge_compute = [&](half8 h) {
        half2v h01 = __builtin_shufflevector(h, h, 0, 1);
        half2v h23 = __builtin_shufflevector(h, h, 2, 3);
        half2v h45 = __builtin_shufflevector(h, h, 4, 5);
        half2v h67 = __builtin_shufflevector(h, h, 6, 7);
        half2v s01 = h01 + xr01, s23 = h23 + xr23, s45 = h45 + xr45, s67 = h67 + xr67;
        half2v l01 = __builtin_elementwise_max(s01, s01 * c02);
        half2v l23 = __builtin_elementwise_max(s23, s23 * c02);
        half2v l45 = __builtin_elementwise_max(s45, s45 * c02);
        half2v l67 = __builtin_elementwise_max(s67, s67 * c02);
        float e = __builtin_amdgcn_fdot2(l01, at01, 0.f, false);
        e = __builtin_amdgcn_fdot2(l23, at23, e, false);
        e = __builtin_amdgcn_fdot2(l45, at45, e, false);
        e = __builtin_amdgcn_fdot2(l67, at67, e, false);
        e += __shfl_xor(e, 1);
        e += __shfl_xor(e, 2);
        e += __shfl_xor(e, 4);
        float pw = __expf(e);
        d += pw;
        #pragma unroll
        for (int k = 0; k < 8; ++k) acc[k] = fmaf(pw, (float)h[k], acc[k]);
    };

    int j0 = __builtin_amdgcn_readfirstlane(offsets[node]);
    int j1 = __builtin_amdgcn_readfirstlane(offsets[node + 1]);
    int deg = j1 - j0;

    // --- fast path: adjacency row in one register (deg<=64) ---
    int fast = min(deg, 64);
    int npf = fast >> 1;                 // pairs handled by the pipeline
    int idxv = 0;
    if (lane < fast) idxv = csr_src[j0 + lane];

    half8 hA, hB;                        // depth-2, named slots (no rotation)
    if (npf > 0) { int s = __shfl(idxv, 0 + H, 64); hA = *(const half8*)(xl + (size_t)s * HIDHC + p * 8); }
    if (npf > 1) { int s = __shfl(idxv, 2 + H, 64); hB = *(const half8*)(xl + (size_t)s * HIDHC + p * 8); }
    int t = 0;
    for (; t + 4 <= npf; t += 2) {       // steady state: compute 2, prefetch 2
        half8 ha = hA, hb = hB;
        { int s = __shfl(idxv, (t + 2) * 2 + H, 64); hA = *(const half8*)(xl + (size_t)s * HIDHC + p * 8); }
        { int s = __shfl(idxv, (t + 3) * 2 + H, 64); hB = *(const half8*)(xl + (size_t)s * HIDHC + p * 8); }
        edge_compute(ha);
        edge_compute(hb);
    }
    if (t + 2 <= npf) {                  // 2 or 3 pairs left
        half8 ha = hA, hb = hB;
        if (t + 2 < npf) { int s = __shfl(idxv, (t + 2) * 2 + H, 64); hA = *(const half8*)(xl + (size_t)s * HIDHC + p * 8); }
        edge_compute(ha);
        edge_compute(hb);
        t += 2;
    }
    if (t < npf) {                       // final pair
        edge_compute(hA);
    }

    // --- remainder: deg>64 pairs (rare) ---
    int j = j0 + (npf << 1);
    for (; j + 2 <= j1; j += 2) {
        int s0 = __builtin_amdgcn_readfirstlane(csr_src[j]);
        int s1 = __builtin_amdgcn_readfirstlane(csr_src[j + 1]);
        int s = H ? s1 : s0;
        half8 h = *(const half8*)(xl + (size_t)s * HIDHC + p * 8);
        edge_compute(h);
    }
    if (j < j1) {                        // odd leftover edge (H==0 half only)
        int s0 = __builtin_amdgcn_readfirstlane(csr_src[j]);
        half8 h = *(const half8*)(xl + (size_t)s0 * HIDHC + p * 8);
        half2v h01 = __builtin_shufflevector(h, h, 0, 1);
        half2v h23 = __builtin_shufflevector(h, h, 2, 3);
        half2v h45 = __builtin_shufflevector(h, h, 4, 5);
        half2v h67 = __builtin_shufflevector(h, h, 6, 7);
        half2v s01 = h01 + xr01, s23 = h23 + xr23, s45 = h45 + xr45, s67 = h67 + xr67;
        half2v l01 = __builtin_elementwise_max(s01, s01 * c02);
        half2v l23 = __builtin_elementwise_max(s23, s23 * c02);
        half2v l45 = __builtin_elementwise_max(s45, s45 * c02);
        half2v l67 = __builtin_elementwise_max(s67, s67 * c02);
        float e = __builtin_amdgcn_fdot2(l01, at01, 0.f, false);
        e = __builtin_amdgcn_fdot2(l23, at23, e, false);
        e = __builtin_amdgcn_fdot2(l45, at45, e, false);
        e = __builtin_amdgcn_fdot2(l67, at67, e, false);
        e += __shfl_xor(e, 1);
        e += __shfl_xor(e, 2);
        e += __shfl_xor(e, 4);
        float pw = (H == 0) ? __expf(e) : 0.f;
        d += pw;
        #pragma unroll
        for (int k = 0; k < 8; ++k) acc[k] = fmaf(pw, (float)h[k], acc[k]);
    }

    d += __shfl_xor(d, 32);
    #pragma unroll
    for (int k = 0; k < 8; ++k) acc[k] += __shfl_xor(acc[k], 32);

    float inv = 1.f / (d + 1e-16f);
    float o[8];
    #pragma unroll
    for (int k = 0; k < 8; ++k) o[k] = acc[k] * inv;

    if (mode == 0) {
        if (H == 0) {
            float4 b0 = *(const float4*)(bias + p * 8);
            float4 b1 = *(const float4*)(bias + p * 8 + 4);
            float bb[8] = { b0.x, b0.y, b0.z, b0.w, b1.x, b1.y, b1.z, b1.w };
            half8 hh;
            #pragma unroll
            for (int k = 0; k < 8; ++k) hh[k] = (_Float16)fmaxf(o[k] + bb[k], 0.f);
            // packed layout write: next gemm's A ([tile][kgroup=p][row][8])
            _Float16* dst = (_Float16*)out0 + (size_t)(node >> 7) * 32768
                          + (size_t)p * 1024 + (size_t)(node & 127) * 8;
            *(half8*)dst = hh;
        }
    } else {
        #pragma unroll
        for (int k = 0; k < 8; ++k) {
            o[k] += __shfl_xor(o[k], 8);
            o[k] += __shfl_xor(o[k], 16);
        }
        if (lane < 8) {
            float4 b0 = *(const float4*)(bias + p * 8);
            float4 b1 = *(const float4*)(bias + p * 8 + 4);
            float bb[8] = { b0.x, b0.y, b0.z, b0.w, b1.x, b1.y, b1.z, b1.w };
            float4 o0, o1;
            o0.x = fmaxf(o[0] * 0.25f + bb[0], 0.f);
            o0.y = fmaxf(o[1] * 0.25f + bb[1], 0.f);
            o0.z = fmaxf(o[2] * 0.25f + bb[2], 0.f);
            o0.w = fmaxf(o[3] * 0.25f + bb[3], 0.f);
            o1.x = fmaxf(o[4] * 0.25f + bb[4], 0.f);
            o1.y = fmaxf(o[5] * 0.25f + bb[5], 0.f);
            o1.z = fmaxf(o[6] * 0.25f + bb[6], 0.f);
            o1.w = fmaxf(o[7] * 0.25f + bb[7], 0.f);
            float* dst = (float*)out0 + (size_t)node * HID + p * 8;
            *(float4*)dst = o0;
            *(float4*)(dst + 4) = o1;
        }
    }
}

// -------------------- final linear: out[N,40] = h2[N,64] @ Wc[64,40] + bc --------------------

__global__ __launch_bounds__(256) void final_linear(
    const float* __restrict__ h2, const float* __restrict__ Wc,
    const float* __restrict__ bc, float* __restrict__ out, int n)
{
    __shared__ float Ws[HID * OUT_DIM];
    __shared__ float bs[OUT_DIM];
    __shared__ float hs[64][HID + 1];

    for (int i = threadIdx.x; i < HID * OUT_DIM; i += 256) Ws[i] = Wc[i];
    if (threadIdx.x < OUT_DIM) bs[threadIdx.x] = bc[threadIdx.x];

    int n0 = blockIdx.x * 64;
    for (int i = threadIdx.x; i < 64 * HID; i += 256) {
        int r = i >> 6, c = i & 63;
        int node = n0 + r;
        hs[r][c] = (node < n) ? h2[(size_t)node * HID + c] : 0.f;
    }
    __syncthreads();

    for (int idx = threadIdx.x; idx < 64 * OUT_DIM; idx += 256) {
        int r = idx / OUT_DIM, o = idx % OUT_DIM;
        int node = n0 + r;
        if (node < n) {
            float s = bs[o];
            #pragma unroll
            for (int c = 0; c < HID; ++c) s = fmaf(hs[r][c], Ws[c * OUT_DIM + o], s);
            out[(size_t)node * OUT_DIM + o] = s;
        }
    }
}

// -------------------- launch --------------------

extern "C" void kernel_launch(void* const* d_in, const int* in_sizes, int n_in,
                              void* d_out, int out_size, void* d_ws, size_t ws_size,
                              hipStream_t stream) {
    const int N = in_sizes[0] / IN_DIM;   // 50000
    const int E = in_sizes[1];            // 800000

    const float* x    = (const float*)d_in[0];
    const int*   src  = (const int*)d_in[1];
    const int*   dst  = (const int*)d_in[2];
    const float* Wl1  = (const float*)d_in[3];
    const float* bl1  = (const float*)d_in[4];
    const float* Wr1  = (const float*)d_in[5];
    const float* br1  = (const float*)d_in[6];
    const float* att1 = (const float*)d_in[7];
    const float* bias1= (const float*)d_in[8];
    const float* Wl2  = (const float*)d_in[9];
    const float* bl2  = (const float*)d_in[10];
    const float* Wr2  = (const float*)d_in[11];
    const float* br2  = (const float*)d_in[12];
    const float* att2 = (const float*)d_in[13];
    const float* bias2= (const float*)d_in[14];
    const float* Wc   = (const float*)d_in[15];
    const float* bc   = (const float*)d_in[16];

    char* ws = (char*)d_ws;
    size_t off = 0;
    const int NT = (N + 127) / 128;                                   // A tiles
    _Float16* xlh = (_Float16*)(ws + off); off += (size_t)N * HIDHC * 2;  // xl fp16 (row-major)
    _Float16* xrh = (_Float16*)(ws + off); off += (size_t)N * HIDHC * 2;  // xr fp16 (row-major)
    _Float16* Af  = (_Float16*)(ws + off); off += (size_t)NT * 32768 * 2; // x / h1 fp16 (PACKED)
    float*    h2  = (float*)(ws + off);    off += (size_t)N * HID * 4;
    _Float16* Wt  = (_Float16*)(ws + off); off += (size_t)4 * 65536 * 2;  // packed weights
    int* deg     = (int*)(ws + off); off += (size_t)N * 4;
    int* offsets = (int*)(ws + off); off += (size_t)(N + 1) * 4;
    int* cursor  = (int*)(ws + off); off += (size_t)N * 4;
    int* csr     = (int*)(ws + off); off += (size_t)E * 4;
    int* bsum    = (int*)(ws + off); off += 256 * 4;

    const int NB = (N + 255) / 256;

    // phase 0: zero deg (+ packed-A tail tile once)
    hipMemsetAsync(deg, 0, (size_t)N * 4, stream);
    if (N & 127)
        hipMemsetAsync(Af + (size_t)(NT - 1) * 32768, 0, 32768 * 2, stream);

    // phase 1: edge histogram || input prep (independent, one dispatch)
    const int nbh = (E + 255) / 256;
    const int n4 = N * HIDHC / 4;
    const int nb_cvt = (n4 + 255) / 256;
    hist_prep<<<nbh + nb_cvt + 1024, 256, 0, stream>>>(
        dst, deg, E, nbh, x, Af, Wl1, Wr1, Wl2, Wr2, Wt, n4, nb_cvt);

    // phase 2: scan (2 dispatches; scan_bsums folded into apply)
    deg_block_reduce<<<NB, 256, 0, stream>>>(deg, bsum, N);
    deg_scan_apply<<<NB, 256, 0, stream>>>(deg, bsum, offsets, cursor, N, NB);

    // phase 3: edge scatter || layer-1 gemm (independent, one dispatch)
    const int KW = 65536;
    const int nbs = (E + 511) / 512;
    gemm_scatter<<<nbs + 2 * NT, 512, 0, stream>>>(Af,
        Wt + 0 * KW, bl1, xlh,
        Wt + 1 * KW, br1, xrh, N, nbs,
        src, dst, cursor, csr, E);

    // layer 1 aggregate
    gat_node<<<(N + 3) / 4, 256, 0, stream>>>(xlh, xrh, att1, bias1, offsets, csr,
                                              (void*)Af, N, 0);
    // layer 2
    gemm_dual<<<dim3(NT, 2), 512, 0, stream>>>(Af,
        Wt + 2 * KW, bl2, xlh,
        Wt + 3 * KW, br2, xrh, N);
    gat_node<<<(N + 3) / 4, 256, 0, stream>>>(xlh, xrh, att2, bias2, offsets, csr,
                                              (void*)h2, N, 1);
    // head
    final_linear<<<(N + 63) / 64, 256, 0, stream>>>(h2, Wc, bc, (float*)d_out, N);
}

// Round 11
// 381.531 us; speedup vs baseline: 1.2623x; 1.0890x over previous
//
#include <hip/hip_runtime.h>
#include <hip/hip_bf16.h>
#include <math.h>

// ---------------------------------------------------------------------------
// GATv2 2-layer + linear head, MI355X (gfx950)
// Round 11: atomic-free scatter via hist-rank.
//   - hist_prep now persists rank[i] = atomicAdd(&deg[dst[i]],1) (the return
//     value is a free unique within-bucket rank; same instruction, sc0).
//   - edge scatter (inside gemm_scatter) becomes pure load/store:
//     csr[offsets[dst[e]] + rank[e]] = src[e]. No atomics, no cursor array.
//     Round-10 counters showed the combined dispatch at 77us with MfmaUtil
//     6%/VALUBusy 7% -- the 800K device-scope atomic chain was the tail.
//   - deg_scan_apply no longer writes cursor (offsets is the same value).
// Everything else identical to round 10 (415.5us): co-scheduled hist||prep,
// scatter||gemm1, inline bsum prefix, round-6 gemm/gat bodies.
// ---------------------------------------------------------------------------

#define IN_DIM 256
#define HIDHC 256   // HEADS*HID
#define HID 64
#define OUT_DIM 40

using half8  = __attribute__((ext_vector_type(8))) _Float16;
using half4  = __attribute__((ext_vector_type(4))) _Float16;
using half2v = __attribute__((ext_vector_type(2))) _Float16;
using f32x4  = __attribute__((ext_vector_type(4))) float;

__device__ __forceinline__ void gload16(const void* g, void* l) {
    __builtin_amdgcn_global_load_lds(
        (const __attribute__((address_space(1))) void*)g,
        (__attribute__((address_space(3))) void*)l, 16, 0, 0);
}

// -------------------- phase 1: hist(+rank) || input prep --------------------
// Packed A layout: (node,k) -> (node>>7)*32768 + (k>>3)*1024 + (node&127)*8 + (k&7)
// Packed W layout: (n,k) -> (n>>7)*32768 + (k>>5)*4096 + ((k>>3)&3)*1024
//                           + (n&127)*8 + (k&7)
__global__ void hist_prep(const int* __restrict__ dst, int* __restrict__ deg,
                          int* __restrict__ rank, int E, int nbh,
                          const float* __restrict__ x, _Float16* __restrict__ Af,
                          const float* __restrict__ W0, const float* __restrict__ W1,
                          const float* __restrict__ W2, const float* __restrict__ W3,
                          _Float16* __restrict__ T, int n4, int nb_cvt) {
    int bid = blockIdx.x;
    if (bid < nbh) {                       // edge histogram + rank capture
        int i = bid * 256 + threadIdx.x;
        if (i < E) rank[i] = atomicAdd(&deg[dst[i]], 1);
    } else if (bid < nbh + nb_cvt) {       // x fp32 -> fp16 packed
        int i = (bid - nbh) * 256 + threadIdx.x;
        if (i >= n4) return;
        float4 v = ((const float4*)x)[i];
        half4 h = { (_Float16)v.x, (_Float16)v.y, (_Float16)v.z, (_Float16)v.w };
        int node = i >> 6;
        int kb = (i & 63) * 4;
        size_t a = (size_t)(node >> 7) * 32768 + (size_t)(kb >> 3) * 1024
                 + (size_t)(node & 127) * 8 + (kb & 7);
        *(half4*)(Af + a) = h;
    } else {                               // weight transpose+pack
        int widx = bid - nbh - nb_cvt;
        int wsel = widx >> 8, k = widx & 255, nn = threadIdx.x;
        const float* Wsel = (wsel == 0) ? W0 : (wsel == 1) ? W1
                          : (wsel == 2) ? W2 : W3;
        float v = Wsel[k * 256 + nn];
        size_t a = (size_t)wsel * 65536
                 + (size_t)(nn >> 7) * 32768 + (size_t)(k >> 5) * 4096
                 + (size_t)((k >> 3) & 3) * 1024 + (size_t)(nn & 127) * 8 + (k & 7);
        T[a] = (_Float16)v;
    }
}

__global__ void deg_block_reduce(const int* __restrict__ deg, int* __restrict__ bsum, int n) {
    int i = blockIdx.x * 256 + threadIdx.x;
    int v = (i < n) ? deg[i] : 0;
    #pragma unroll
    for (int off = 32; off; off >>= 1) v += __shfl_xor(v, off, 64);
    __shared__ int ws[4];
    int lane = threadIdx.x & 63, wid = threadIdx.x >> 6;
    if (lane == 0) ws[wid] = v;
    __syncthreads();
    if (threadIdx.x == 0) bsum[blockIdx.x] = ws[0] + ws[1] + ws[2] + ws[3];
}

// apply with INLINE block-prefix over bsum (nb<=256); offsets only (no cursor).
__global__ void deg_scan_apply(const int* __restrict__ deg, const int* __restrict__ bsum,
                               int* __restrict__ offsets, int n, int nb) {
    int tid = threadIdx.x;
    int lane = tid & 63, wid = tid >> 6;

    __shared__ int pws[4];
    __shared__ int sadd;
    int pv = (tid < nb && tid < (int)blockIdx.x) ? bsum[tid] : 0;
    #pragma unroll
    for (int off = 32; off; off >>= 1) pv += __shfl_xor(pv, off, 64);
    if (lane == 0) pws[wid] = pv;
    __syncthreads();
    if (tid == 0) sadd = pws[0] + pws[1] + pws[2] + pws[3];
    __syncthreads();

    int i = blockIdx.x * 256 + tid;
    int v = (i < n) ? deg[i] : 0;
    int inc = v;
    #pragma unroll
    for (int off = 1; off < 64; off <<= 1) {
        int t = __shfl_up(inc, off, 64);
        if (lane >= off) inc += t;
    }
    __shared__ int ws[4];
    if (lane == 63) ws[wid] = inc;
    __syncthreads();
    int add = sadd;
    for (int w = 0; w < wid; ++w) add += ws[w];
    int incl = inc + add;
    if (i < n) offsets[i + 1] = incl;
    if (i == 0) offsets[0] = 0;
}

// -------------------- dual MFMA GEMM tile (device body, round-6 proven) -----

__device__ __forceinline__ void gemm_tile(
    const _Float16* __restrict__ Apk,
    const _Float16* __restrict__ W0, const float* __restrict__ b0, _Float16* __restrict__ C0,
    const _Float16* __restrict__ W1, const float* __restrict__ b1, _Float16* __restrict__ C1,
    int M, int bx, int by, _Float16* sA, _Float16* sW)
{
    int tid = threadIdx.x;
    int bm = bx * 128;
    int bn = by * 128;

    int lane = tid & 63, w = tid >> 6;       // 8 waves
    int z  = w >> 2, wq = w & 3;
    int r = lane & 15, q = lane >> 4;
    int m0 = (wq >> 1) * 64, n0 = (wq & 1) * 64;

    const _Float16* Abase = Apk + (size_t)bx * 32768;
    const _Float16* W0b   = W0  + (size_t)by * 32768;
    const _Float16* W1b   = W1  + (size_t)by * 32768;
    int go = tid * 8;                        // granule offset (elements)

    f32x4 acc[4][4];
    #pragma unroll
    for (int i = 0; i < 4; ++i)
        #pragma unroll
        for (int j = 0; j < 4; ++j) acc[i][j] = (f32x4)0.f;

    gload16(Abase + go, sA + go);
    gload16(W0b + go, sW + go);
    gload16(W1b + go, sW + 4096 + go);
    __builtin_amdgcn_s_waitcnt(0);   // drain LDS-DMA
    __syncthreads();

    #pragma unroll 1
    for (int kt = 0; kt < 8; ++kt) {
        int buf = kt & 1;
        if (kt < 7) {
            int k0 = (kt + 1) * 4096;
            gload16(Abase + k0 + go, sA + (buf ^ 1) * 4096 + go);
            gload16(W0b + k0 + go, sW + ((buf ^ 1) * 2 + 0) * 4096 + go);
            gload16(W1b + k0 + go, sW + ((buf ^ 1) * 2 + 1) * 4096 + go);
        }
        half8 a[4], b[4];
        #pragma unroll
        for (int i = 0; i < 4; ++i) {
            a[i] = *(const half8*)(sA + buf * 4096 + (q * 128 + m0 + i * 16 + r) * 8);
            b[i] = *(const half8*)(sW + (buf * 2 + z) * 4096 + (q * 128 + n0 + i * 16 + r) * 8);
        }
        #pragma unroll
        for (int i = 0; i < 4; ++i)
            #pragma unroll
            for (int j = 0; j < 4; ++j)
                acc[i][j] = __builtin_amdgcn_mfma_f32_16x16x32_f16(a[i], b[j], acc[i][j], 0, 0, 0);
        __builtin_amdgcn_s_waitcnt(0);   // drain prefetch DMA before buffer swap
        __syncthreads();
    }

    const float* bias = z ? b1 : b0;
    _Float16*    C    = z ? C1 : C0;

    float bv[4];
    #pragma unroll
    for (int j = 0; j < 4; ++j) bv[j] = bias[bn + n0 + j * 16 + r];
    #pragma unroll
    for (int i = 0; i < 4; ++i) {
        #pragma unroll
        for (int reg = 0; reg < 4; ++reg) {
            int orow = bm + m0 + i * 16 + q * 4 + reg;
            if (orow < M) {
                #pragma unroll
                for (int j = 0; j < 4; ++j)
                    C[(size_t)orow * 256 + bn + n0 + j * 16 + r] =
                        (_Float16)(acc[i][j][reg] + bv[j]);
            }
        }
    }
}

__global__ __launch_bounds__(512) void gemm_dual(
    const _Float16* __restrict__ Apk,
    const _Float16* __restrict__ W0, const float* __restrict__ b0, _Float16* __restrict__ C0,
    const _Float16* __restrict__ W1, const float* __restrict__ b1, _Float16* __restrict__ C1,
    int M)
{
    __shared__ __align__(16) _Float16 sA[2 * 4096];
    __shared__ __align__(16) _Float16 sW[2 * 2 * 4096];
    gemm_tile(Apk, W0, b0, C0, W1, b1, C1, M, blockIdx.x, blockIdx.y, sA, sW);
}

// layer-1 gemm co-scheduled with ATOMIC-FREE edge scatter.
__global__ __launch_bounds__(512) void gemm_scatter(
    const _Float16* __restrict__ Apk,
    const _Float16* __restrict__ W0, const float* __restrict__ b0, _Float16* __restrict__ C0,
    const _Float16* __restrict__ W1, const float* __restrict__ b1, _Float16* __restrict__ C1,
    int M, int nbs,
    const int* __restrict__ src, const int* __restrict__ dst,
    const int* __restrict__ rank, const int* __restrict__ offsets,
    int* __restrict__ csr_src, int E)
{
    __shared__ __align__(16) _Float16 sA[2 * 4096];
    __shared__ __align__(16) _Float16 sW[2 * 2 * 4096];
    if ((int)blockIdx.x < nbs) {           // edge scatter: pure load/store
        int e = blockIdx.x * 512 + threadIdx.x;
        if (e < E) {
            int d = dst[e];
            csr_src[offsets[d] + rank[e]] = src[e];
        }
        return;
    }
    int g = blockIdx.x - nbs;
    gemm_tile(Apk, W0, b0, C0, W1, b1, C1, M, g >> 1, g & 1, sA, sW);
}

// -------------------- GAT node kernel: half-wave-per-edge ---------------------

__global__ __launch_bounds__(256) void gat_node(
    const _Float16* __restrict__ xl, const _Float16* __restrict__ xr,
    const float* __restrict__ att, const float* __restrict__ bias,
    const int* __restrict__ offsets, const int* __restrict__ csr_src,
    void* __restrict__ out0, int n, int mode)
{
    int wid = threadIdx.x >> 6;
    int node = (blockIdx.x << 2) + wid;
    if (node >= n) return;
    int lane = threadIdx.x & 63;
    int H = lane >> 5;
    int p = lane & 31;

    const half2v c02 = { (_Float16)0.2f, (_Float16)0.2f };

    half8 xrh = *(const half8*)(xr + (size_t)node * HIDHC + p * 8);
    half2v xr01 = __builtin_shufflevector(xrh, xrh, 0, 1);
    half2v xr23 = __builtin_shufflevector(xrh, xrh, 2, 3);
    half2v xr45 = __builtin_shufflevector(xrh, xrh, 4, 5);
    half2v xr67 = __builtin_shufflevector(xrh, xrh, 6, 7);

    float4 af0 = *(const float4*)(att + p * 8);
    float4 af1 = *(const float4*)(att + p * 8 + 4);
    half2v at01 = { (_Float16)af0.x, (_Float16)af0.y };
    half2v at23 = { (_Float16)af0.z, (_Float16)af0.w };
    half2v at45 = { (_Float16)af1.x, (_Float16)af1.y };
    half2v at67 = { (_Float16)af1.z, (_Float16)af1.w };

    float acc[8];
    #pragma unroll
    for (int k = 0; k < 8; ++k) acc[k] = 0.f;
    float d = 0.f;

    auto edge_compute = [&](half8 h) {
        half2v h01 = __builtin_shufflevector(h, h, 0, 1);
        half2v h23 = __builtin_shufflevector(h, h, 2, 3);
        half2v h45 = __builtin_shufflevector(h, h, 4, 5);
        half2v h67 = __builtin_shufflevector(h, h, 6, 7);
        half2v s01 = h01 + xr01, s23 = h23 + xr23, s45 = h45 + xr45, s67 = h67 + xr67;
        half2v l01 = __builtin_elementwise_max(s01, s01 * c02);
        half2v l23 = __builtin_elementwise_max(s23, s23 * c02);
        half2v l45 = __builtin_elementwise_max(s45, s45 * c02);
        half2v l67 = __builtin_elementwise_max(s67, s67 * c02);
        float e = __builtin_amdgcn_fdot2(l01, at01, 0.f, false);
        e = __builtin_amdgcn_fdot2(l23, at23, e, false);
        e = __builtin_amdgcn_fdot2(l45, at45, e, false);
        e = __builtin_amdgcn_fdot2(l67, at67, e, false);
        e += __shfl_xor(e, 1);
        e += __shfl_xor(e, 2);
        e += __shfl_xor(e, 4);
        float pw = __expf(e);
        d += pw;
        #pragma unroll
        for (int k = 0; k < 8; ++k) acc[k] = fmaf(pw, (float)h[k], acc[k]);
    };

    int j0 = __builtin_amdgcn_readfirstlane(offsets[node]);
    int j1 = __builtin_amdgcn_readfirstlane(offsets[node + 1]);
    int deg = j1 - j0;

    // --- fast path: adjacency row in one register (deg<=64) ---
    int fast = min(deg, 64);
    int npf = fast >> 1;                 // pairs handled by the pipeline
    int idxv = 0;
    if (lane < fast) idxv = csr_src[j0 + lane];

    half8 hA, hB;                        // depth-2, named slots (no rotation)
    if (npf > 0) { int s = __shfl(idxv, 0 + H, 64); hA = *(const half8*)(xl + (size_t)s * HIDHC + p * 8); }
    if (npf > 1) { int s = __shfl(idxv, 2 + H, 64); hB = *(const half8*)(xl + (size_t)s * HIDHC + p * 8); }
    int t = 0;
    for (; t + 4 <= npf; t += 2) {       // steady state: compute 2, prefetch 2
        half8 ha = hA, hb = hB;
        { int s = __shfl(idxv, (t + 2) * 2 + H, 64); hA = *(const half8*)(xl + (size_t)s * HIDHC + p * 8); }
        { int s = __shfl(idxv, (t + 3) * 2 + H, 64); hB = *(const half8*)(xl + (size_t)s * HIDHC + p * 8); }
        edge_compute(ha);
        edge_compute(hb);
    }
    if (t + 2 <= npf) {                  // 2 or 3 pairs left
        half8 ha = hA, hb = hB;
        if (t + 2 < npf) { int s = __shfl(idxv, (t + 2) * 2 + H, 64); hA = *(const half8*)(xl + (size_t)s * HIDHC + p * 8); }
        edge_compute(ha);
        edge_compute(hb);
        t += 2;
    }
    if (t < npf) {                       // final pair
        edge_compute(hA);
    }

    // --- remainder: deg>64 pairs (rare) ---
    int j = j0 + (npf << 1);
    for (; j + 2 <= j1; j += 2) {
        int s0 = __builtin_amdgcn_readfirstlane(csr_src[j]);
        int s1 = __builtin_amdgcn_readfirstlane(csr_src[j + 1]);
        int s = H ? s1 : s0;
        half8 h = *(const half8*)(xl + (size_t)s * HIDHC + p * 8);
        edge_compute(h);
    }
    if (j < j1) {                        // odd leftover edge (H==0 half only)
        int s0 = __builtin_amdgcn_readfirstlane(csr_src[j]);
        half8 h = *(const half8*)(xl + (size_t)s0 * HIDHC + p * 8);
        half2v h01 = __builtin_shufflevector(h, h, 0, 1);
        half2v h23 = __builtin_shufflevector(h, h, 2, 3);
        half2v h45 = __builtin_shufflevector(h, h, 4, 5);
        half2v h67 = __builtin_shufflevector(h, h, 6, 7);
        half2v s01 = h01 + xr01, s23 = h23 + xr23, s45 = h45 + xr45, s67 = h67 + xr67;
        half2v l01 = __builtin_elementwise_max(s01, s01 * c02);
        half2v l23 = __builtin_elementwise_max(s23, s23 * c02);
        half2v l45 = __builtin_elementwise_max(s45, s45 * c02);
        half2v l67 = __builtin_elementwise_max(s67, s67 * c02);
        float e = __builtin_amdgcn_fdot2(l01, at01, 0.f, false);
        e = __builtin_amdgcn_fdot2(l23, at23, e, false);
        e = __builtin_amdgcn_fdot2(l45, at45, e, false);
        e = __builtin_amdgcn_fdot2(l67, at67, e, false);
        e += __shfl_xor(e, 1);
        e += __shfl_xor(e, 2);
        e += __shfl_xor(e, 4);
        float pw = (H == 0) ? __expf(e) : 0.f;
        d += pw;
        #pragma unroll
        for (int k = 0; k < 8; ++k) acc[k] = fmaf(pw, (float)h[k], acc[k]);
    }

    d += __shfl_xor(d, 32);
    #pragma unroll
    for (int k = 0; k < 8; ++k) acc[k] += __shfl_xor(acc[k], 32);

    float inv = 1.f / (d + 1e-16f);
    float o[8];
    #pragma unroll
    for (int k = 0; k < 8; ++k) o[k] = acc[k] * inv;

    if (mode == 0) {
        if (H == 0) {
            float4 b0 = *(const float4*)(bias + p * 8);
            float4 b1 = *(const float4*)(bias + p * 8 + 4);
            float bb[8] = { b0.x, b0.y, b0.z, b0.w, b1.x, b1.y, b1.z, b1.w };
            half8 hh;
            #pragma unroll
            for (int k = 0; k < 8; ++k) hh[k] = (_Float16)fmaxf(o[k] + bb[k], 0.f);
            // packed layout write: next gemm's A ([tile][kgroup=p][row][8])
            _Float16* dstp = (_Float16*)out0 + (size_t)(node >> 7) * 32768
                           + (size_t)p * 1024 + (size_t)(node & 127) * 8;
            *(half8*)dstp = hh;
        }
    } else {
        #pragma unroll
        for (int k = 0; k < 8; ++k) {
            o[k] += __shfl_xor(o[k], 8);
            o[k] += __shfl_xor(o[k], 16);
        }
        if (lane < 8) {
            float4 b0 = *(const float4*)(bias + p * 8);
            float4 b1 = *(const float4*)(bias + p * 8 + 4);
            float bb[8] = { b0.x, b0.y, b0.z, b0.w, b1.x, b1.y, b1.z, b1.w };
            float4 o0, o1;
            o0.x = fmaxf(o[0] * 0.25f + bb[0], 0.f);
            o0.y = fmaxf(o[1] * 0.25f + bb[1], 0.f);
            o0.z = fmaxf(o[2] * 0.25f + bb[2], 0.f);
            o0.w = fmaxf(o[3] * 0.25f + bb[3], 0.f);
            o1.x = fmaxf(o[4] * 0.25f + bb[4], 0.f);
            o1.y = fmaxf(o[5] * 0.25f + bb[5], 0.f);
            o1.z = fmaxf(o[6] * 0.25f + bb[6], 0.f);
            o1.w = fmaxf(o[7] * 0.25f + bb[7], 0.f);
            float* dstp = (float*)out0 + (size_t)node * HID + p * 8;
            *(float4*)dstp = o0;
            *(float4*)(dstp + 4) = o1;
        }
    }
}

// -------------------- final linear: out[N,40] = h2[N,64] @ Wc[64,40] + bc --------------------

__global__ __launch_bounds__(256) void final_linear(
    const float* __restrict__ h2, const float* __restrict__ Wc,
    const float* __restrict__ bc, float* __restrict__ out, int n)
{
    __shared__ float Ws[HID * OUT_DIM];
    __shared__ float bs[OUT_DIM];
    __shared__ float hs[64][HID + 1];

    for (int i = threadIdx.x; i < HID * OUT_DIM; i += 256) Ws[i] = Wc[i];
    if (threadIdx.x < OUT_DIM) bs[threadIdx.x] = bc[threadIdx.x];

    int n0 = blockIdx.x * 64;
    for (int i = threadIdx.x; i < 64 * HID; i += 256) {
        int r = i >> 6, c = i & 63;
        int node = n0 + r;
        hs[r][c] = (node < n) ? h2[(size_t)node * HID + c] : 0.f;
    }
    __syncthreads();

    for (int idx = threadIdx.x; idx < 64 * OUT_DIM; idx += 256) {
        int r = idx / OUT_DIM, o = idx % OUT_DIM;
        int node = n0 + r;
        if (node < n) {
            float s = bs[o];
            #pragma unroll
            for (int c = 0; c < HID; ++c) s = fmaf(hs[r][c], Ws[c * OUT_DIM + o], s);
            out[(size_t)node * OUT_DIM + o] = s;
        }
    }
}

// -------------------- launch --------------------

extern "C" void kernel_launch(void* const* d_in, const int* in_sizes, int n_in,
                              void* d_out, int out_size, void* d_ws, size_t ws_size,
                              hipStream_t stream) {
    const int N = in_sizes[0] / IN_DIM;   // 50000
    const int E = in_sizes[1];            // 800000

    const float* x    = (const float*)d_in[0];
    const int*   src  = (const int*)d_in[1];
    const int*   dst  = (const int*)d_in[2];
    const float* Wl1  = (const float*)d_in[3];
    const float* bl1  = (const float*)d_in[4];
    const float* Wr1  = (const float*)d_in[5];
    const float* br1  = (const float*)d_in[6];
    const float* att1 = (const float*)d_in[7];
    const float* bias1= (const float*)d_in[8];
    const float* Wl2  = (const float*)d_in[9];
    const float* bl2  = (const float*)d_in[10];
    const float* Wr2  = (const float*)d_in[11];
    const float* br2  = (const float*)d_in[12];
    const float* att2 = (const float*)d_in[13];
    const float* bias2= (const float*)d_in[14];
    const float* Wc   = (const float*)d_in[15];
    const float* bc   = (const float*)d_in[16];

    char* ws = (char*)d_ws;
    size_t off = 0;
    const int NT = (N + 127) / 128;                                   // A tiles
    _Float16* xlh = (_Float16*)(ws + off); off += (size_t)N * HIDHC * 2;  // xl fp16 (row-major)
    _Float16* xrh = (_Float16*)(ws + off); off += (size_t)N * HIDHC * 2;  // xr fp16 (row-major)
    _Float16* Af  = (_Float16*)(ws + off); off += (size_t)NT * 32768 * 2; // x / h1 fp16 (PACKED)
    float*    h2  = (float*)(ws + off);    off += (size_t)N * HID * 4;
    _Float16* Wt  = (_Float16*)(ws + off); off += (size_t)4 * 65536 * 2;  // packed weights
    int* deg     = (int*)(ws + off); off += (size_t)N * 4;
    int* offsets = (int*)(ws + off); off += (size_t)(N + 1) * 4;
    int* rank    = (int*)(ws + off); off += (size_t)E * 4;
    int* csr     = (int*)(ws + off); off += (size_t)E * 4;
    int* bsum    = (int*)(ws + off); off += 256 * 4;

    const int NB = (N + 255) / 256;

    // phase 0: zero deg (+ packed-A tail tile once)
    hipMemsetAsync(deg, 0, (size_t)N * 4, stream);
    if (N & 127)
        hipMemsetAsync(Af + (size_t)(NT - 1) * 32768, 0, 32768 * 2, stream);

    // phase 1: edge histogram(+rank) || input prep
    const int nbh = (E + 255) / 256;
    const int n4 = N * HIDHC / 4;
    const int nb_cvt = (n4 + 255) / 256;
    hist_prep<<<nbh + nb_cvt + 1024, 256, 0, stream>>>(
        dst, deg, rank, E, nbh, x, Af, Wl1, Wr1, Wl2, Wr2, Wt, n4, nb_cvt);

    // phase 2: scan (2 dispatches)
    deg_block_reduce<<<NB, 256, 0, stream>>>(deg, bsum, N);
    deg_scan_apply<<<NB, 256, 0, stream>>>(deg, bsum, offsets, N, NB);

    // phase 3: atomic-free edge scatter || layer-1 gemm
    const int KW = 65536;
    const int nbs = (E + 511) / 512;
    gemm_scatter<<<nbs + 2 * NT, 512, 0, stream>>>(Af,
        Wt + 0 * KW, bl1, xlh,
        Wt + 1 * KW, br1, xrh, N, nbs,
        src, dst, rank, offsets, csr, E);

    // layer 1 aggregate
    gat_node<<<(N + 3) / 4, 256, 0, stream>>>(xlh, xrh, att1, bias1, offsets, csr,
                                              (void*)Af, N, 0);
    // layer 2
    gemm_dual<<<dim3(NT, 2), 512, 0, stream>>>(Af,
        Wt + 2 * KW, bl2, xlh,
        Wt + 3 * KW, br2, xrh, N);
    gat_node<<<(N + 3) / 4, 256, 0, stream>>>(xlh, xrh, att2, bias2, offsets, csr,
                                              (void*)h2, N, 1);
    // head
    final_linear<<<(N + 63) / 64, 256, 0, stream>>>(h2, Wc, bc, (float*)d_out, N);
}